// Round 6
// baseline (2678.540 us; speedup 1.0000x reference)
//
#include <hip/hip_runtime.h>
#include <hip/hip_fp16.h>
#include <math.h>

#define TT 512
#define BB 16
#define EE 100
#define HD 500
#define NEG (-10000.0f)
#define SENT64 0xFFFFFFFFFFFFFFFFull
#define SENT32 0xFFFFFFFFu

typedef __attribute__((ext_vector_type(8))) short short8;
typedef __attribute__((ext_vector_type(4))) float f32x4;
typedef __attribute__((ext_vector_type(4))) unsigned int u32x4;
typedef __attribute__((ext_vector_type(2))) unsigned int u32x2;

__device__ inline short f2bf(float f) {
    unsigned u = __builtin_bit_cast(unsigned, f);
    unsigned r = (u + 0x7fffu + ((u >> 16) & 1u)) >> 16;
    return (short)r;
}
__device__ inline unsigned short f2h(float f) {
    __half h = __float2half(f);
    return __builtin_bit_cast(unsigned short, h);
}
__device__ inline float h2f(unsigned short u) {
    __half h = __builtin_bit_cast(__half, u);
    return __half2float(h);
}
__device__ inline float bf2f(unsigned short u) {
    return __builtin_bit_cast(float, ((unsigned)u) << 16);
}
// fast sigmoid/tanh via v_exp+v_rcp (r2/r5-verified: absmax 0.0). Saturation correct:
// exp overflow -> inf -> rcp -> 0 -> +/-1.
__device__ inline float sigm_fast(float x) {
    return __builtin_amdgcn_rcpf(1.f + __expf(-x));
}
__device__ inline float tanh_fast(float x) {
    return 1.f - 2.f * __builtin_amdgcn_rcpf(__expf(2.f * x) + 1.f);
}
// MALL write-through 2B store (same visibility mechanics as the h-publish stores)
__device__ inline void store_u16_wt(unsigned short* p, unsigned short v) {
    asm volatile("global_store_short %0, %1, off sc0 sc1" :: "v"(p), "v"((unsigned)v) : "memory");
}

// ============ PREP: maxlen + sentfill + gcnt-zero + embed + wconv x2 + padzero =====
// All tasks are mutually independent; one dispatch replaces six. Block-range switch.
#define NSENT64B 8208     // ceil(2101248/256)
#define NEMB     4096
#define NWC0     2000
#define NWC1     16000
#define NPAD     384
__global__ __launch_bounds__(256) void prep_kernel(
    const int* __restrict__ x, int* __restrict__ mlen,
    unsigned long long* __restrict__ sentp, int* __restrict__ gcnt,
    const float* __restrict__ EW, unsigned short* __restrict__ XS,
    const float* __restrict__ Wih0, unsigned short* __restrict__ Wb0,
    const float* __restrict__ Wih1, unsigned short* __restrict__ Wb1,
    int* __restrict__ H0pad) {
    int bid = blockIdx.x;
    int tid = threadIdx.x;
    if (bid == 0) {
        // maxlen (t = tid and tid+256) + gcnt zero
        __shared__ int mx;
        if (tid == 0) mx = 1;
        if (tid < 128)
            __hip_atomic_store(gcnt + tid, 0, __ATOMIC_RELAXED, __HIP_MEMORY_SCOPE_AGENT);
        __syncthreads();
        int any0 = 0, any1 = 0;
        for (int b = 0; b < BB; ++b) {
            any0 |= (x[b * TT + tid] > 0);
            any1 |= (x[b * TT + tid + 256] > 0);
        }
        if (any0) atomicMax(&mx, tid + 1);
        if (any1) atomicMax(&mx, tid + 257);
        __syncthreads();
        if (tid == 0) mlen[0] = mx;
        return;
    }
    bid -= 1;
    if (bid < NSENT64B) {
        int i = bid * 256 + tid;
        if (i < 2101248)
            __hip_atomic_store(sentp + i, SENT64, __ATOMIC_RELAXED, __HIP_MEMORY_SCOPE_AGENT);
        return;
    }
    bid -= NSENT64B;
    if (bid < NEMB) {
        int idx = bid * 256 + tid;       // < 8192*128
        int e = idx & 127;
        int r = idx >> 7;
        int t = r >> 4;
        int b = r & 15;
        unsigned short v = 0;
        if (e < EE) {
            int tok = x[b * TT + t];
            v = (unsigned short)f2bf(EW[(size_t)tok * EE + e]);
        }
        XS[idx] = v;
        return;
    }
    bid -= NEMB;
    if (bid < NWC0) {
        int i = bid * 256 + tid;         // < 512000, Ksrc=100 Kpad=128
        int r = i >> 7;
        int k = i & 127;
        Wb0[i] = (k < 100) ? (unsigned short)f2bf(Wih0[(size_t)r * 100 + k]) : 0;
        return;
    }
    bid -= NWC0;
    if (bid < NWC1) {
        int i = bid * 256 + tid;         // < 4096000, Ksrc=1000 Kpad=1024
        int r = i >> 10;
        int k = i & 1023;
        Wb1[i] = (k < 1000) ? (unsigned short)f2bf(Wih1[(size_t)r * 1000 + k]) : 0;
        return;
    }
    bid -= NWC1;
    {
        int i = bid * 256 + tid;         // < 98304
        if (i < 8192 * 12) {
            int r = i / 12, c = i - r * 12;
            H0pad[r * 512 + 500 + c] = 0;
        }
    }
}

// ------- sentinel refill between layers (also re-zeroes tile counters) -------------
__global__ void sentfill_kernel(unsigned long long* __restrict__ p, int n,
                                int* __restrict__ cnt) {
    int i = blockIdx.x * 256 + threadIdx.x;
    if (i < n)
        __hip_atomic_store(p + i, SENT64, __ATOMIC_RELAXED, __HIP_MEMORY_SCOPE_AGENT);
    if (cnt && blockIdx.x == 0 && threadIdx.x < 128)
        __hip_atomic_store(cnt + threadIdx.x, 0, __ATOMIC_RELAXED, __HIP_MEMORY_SCOPE_AGENT);
}

// ------------- bf16 MFMA GEMM body (fused producer) --------------------------------
// A: (8192, Kpad) bf16. W: (2, 2000, Kpad) bf16.
// OUTPUT LAYOUT (round-6): Gh[row][kk*4 + gate] fp16 (gate-packed: the 4 gate values
// of one (row,kk) are adjacent) -> consumer loads one dwordx2 per (b,k).
// Write-through sc0sc1 stores, vmcnt drain, then release counter[z*64+bx].
__device__ __forceinline__ void gemm_body(
    const unsigned short* __restrict__ A, const unsigned short* __restrict__ W,
    const float* __restrict__ b1, const float* __restrict__ b2,
    unsigned short* __restrict__ C, int Kpad, int bx, int by, int z,
    int* gcnt) {
    __shared__ __align__(16) unsigned short AsS[128 * 40];
    __shared__ __align__(16) unsigned short WsS[64 * 40];
    const int tid = threadIdx.x;
    const int lane = tid & 63;
    const int w = tid >> 6;
    const int quad = lane >> 4;
    const int nl = lane & 15;
    const int bm0 = bx * 128;
    const int n0 = by * 64;

    const unsigned short* Wz = W + (size_t)z * 2000 * Kpad;
    unsigned short* Cz = C + (size_t)z * 8192 * 2000;
    const float* b1z = b1 + (size_t)z * 2000;
    const float* b2z = b2 + (size_t)z * 2000;

    f32x4 acc[2][4];
#pragma unroll
    for (int mt = 0; mt < 2; ++mt)
#pragma unroll
        for (int nt = 0; nt < 4; ++nt) acc[mt][nt] = (f32x4){0.f, 0.f, 0.f, 0.f};

    const int arow = tid >> 2;
    const int kc = tid & 3;
    const int wn = n0 + arow;
    const bool wok = (wn < 2000);

    const unsigned short* Ap0 = A + (size_t)(bm0 + arow) * Kpad + kc * 8;
    const unsigned short* Ap1 = A + (size_t)(bm0 + 64 + arow) * Kpad + kc * 8;
    const unsigned short* Wp  = Wz + (size_t)(wok ? wn : 0) * Kpad + kc * 8;

    // preload tile 0
    short8 av0 = *(const short8*)(Ap0);
    short8 av1 = *(const short8*)(Ap1);
    short8 wv = {0, 0, 0, 0, 0, 0, 0, 0};
    if (wok) wv = *(const short8*)(Wp);

    for (int k0 = 0; k0 < Kpad; k0 += 32) {
        __syncthreads();           // prior iteration's fragment reads done (WAR)
        *(short8*)&AsS[arow * 40 + kc * 8] = av0;
        *(short8*)&AsS[(64 + arow) * 40 + kc * 8] = av1;
        *(short8*)&WsS[arow * 40 + kc * 8] = wv;
        __syncthreads();

        // issue next tile's loads now; latency hides under LDS reads + MFMA
        if (k0 + 32 < Kpad) {
            av0 = *(const short8*)(Ap0 + k0 + 32);
            av1 = *(const short8*)(Ap1 + k0 + 32);
            if (wok) wv = *(const short8*)(Wp + k0 + 32);
        }

        short8 af[2], bfr[4];
#pragma unroll
        for (int mt = 0; mt < 2; ++mt)
            af[mt] = *(const short8*)&AsS[(w * 32 + mt * 16 + nl) * 40 + quad * 8];
#pragma unroll
        for (int nt = 0; nt < 4; ++nt)
            bfr[nt] = *(const short8*)&WsS[(nt * 16 + nl) * 40 + quad * 8];
#pragma unroll
        for (int mt = 0; mt < 2; ++mt)
#pragma unroll
            for (int nt = 0; nt < 4; ++nt)
                acc[mt][nt] = __builtin_amdgcn_mfma_f32_16x16x32_bf16(
                    af[mt], bfr[nt], acc[mt][nt], 0, 0, 0);
    }

#pragma unroll
    for (int nt = 0; nt < 4; ++nt) {
        int n = n0 + nt * 16 + nl;       // logical n = gate*500 + kk
        if (n < 2000) {
            float bb = b1z[n] + b2z[n];
            int g = (n >= 1000) ? ((n >= 1500) ? 3 : 2) : ((n >= 500) ? 1 : 0);
            int col = (n - g * 500) * 4 + g;   // gate-packed column
#pragma unroll
            for (int mt = 0; mt < 2; ++mt) {
                int mbase = bm0 + w * 32 + mt * 16 + quad * 4;
#pragma unroll
                for (int reg = 0; reg < 4; ++reg)
                    store_u16_wt(&Cz[(size_t)(mbase + reg) * 2000 + col],
                                 f2h(acc[mt][nt][reg] + bb));
            }
        }
    }
    // drain asm stores, block-wide complete, release tile counter (agent atomic)
    asm volatile("s_waitcnt vmcnt(0)" ::: "memory");
    __syncthreads();
    if (tid == 0)
        __hip_atomic_fetch_add(&gcnt[z * 64 + bx], 1,
                               __ATOMIC_RELAXED, __HIP_MEMORY_SCOPE_AGENT);
}

// ---------------- persistent-weight recurrence, bf16 MFMA, DATA-IS-FLAG sync -------
// Proven protocol (r0/r4/r5). G is gate-packed: one dwordx2 per (b,k) yields all 4
// gates; loads issued sc0sc1, completion folded into the poll's vmcnt(0) via "+v".
// gcnt gating: before prefetching a NEW 8-step row tile, spin until
// counter[dir*64+tile] == 32 (all 32 column tiles written through). ~once per 8 steps.
__device__ __forceinline__ void rec_body(
    const unsigned short* __restrict__ G, const float* __restrict__ Whh,
    const int* __restrict__ x, const float* __restrict__ h0,
    const float* __restrict__ c0, int layerbase,
    unsigned short* __restrict__ Hout, unsigned short* __restrict__ hseq,
    const int* __restrict__ mlen, int* gcnt, int blk)
{
    const int dir = blk >> 4;
    const int bsl = blk & 15;
    const int k0 = bsl * 32;
    const int tid = threadIdx.x;
    const int lane = tid & 63;
    const int w = tid >> 6;          // wave 0..3
    const int quad = lane >> 4;      // 0..3
    const int nl = lane & 15;
    const int L = mlen[0];           // 1..512

    const float* Wd = Whh + (size_t)dir * 2000 * HD;
    const unsigned short* Gd = G + (size_t)dir * TT * BB * 2000;
    unsigned short* hdir = hseq + (size_t)dir * (TT + 1) * 8192;

    __shared__ __align__(16) unsigned short hstage[8192];
    __shared__ float sg[4][32][17];

    // ---- load weights into registers as B fragments (bf16) ----
    short8 bf[2][16];
#pragma unroll
    for (int tl = 0; tl < 2; ++tl) {
        int tt = w * 2 + tl;
        int r = tt * 16 + nl;          // 0..127 local gate row
        int g = r >> 5;                // gate 0..3
        int lkr = r & 31;
        int kk = k0 + lkr;             // output h index
        const float* wrow = (kk < HD) ? (Wd + (size_t)(g * HD + kk) * HD) : (const float*)0;
#pragma unroll
        for (int ks = 0; ks < 16; ++ks) {
            int kg0 = ks * 32 + quad * 8;
            short8 v;
            if (wrow && kg0 + 8 <= HD) {
                float4 f0 = *(const float4*)(wrow + kg0);
                float4 f1 = *(const float4*)(wrow + kg0 + 4);
                v[0] = f2bf(f0.x); v[1] = f2bf(f0.y); v[2] = f2bf(f0.z); v[3] = f2bf(f0.w);
                v[4] = f2bf(f1.x); v[5] = f2bf(f1.y); v[6] = f2bf(f1.z); v[7] = f2bf(f1.w);
            } else {
#pragma unroll
                for (int j = 0; j < 8; ++j) {
                    int kg = kg0 + j;
                    float f = (wrow && kg < HD) ? wrow[kg] : 0.f;
                    v[j] = f2bf(f);
                }
            }
            bf[tl][ks] = v;
        }
    }

    // ---- per-thread persistent state: 2 (b,k) pairs, same k different b ----
    const int lk = tid & 31;
    const int k  = k0 + lk;
    const bool kok = (k < HD);
    const int b0v = tid >> 5;          // 0..7
    const int b1v = 8 + (tid >> 5);    // 8..15
    float h_st[2] = {0.f, 0.f}, c_st[2] = {0.f, 0.f};
    if (kok) {
        size_t base0 = (size_t)(layerbase + dir) * BB * HD + (size_t)b0v * HD + k;
        size_t base1 = (size_t)(layerbase + dir) * BB * HD + (size_t)b1v * HD + k;
        h_st[0] = h0[base0]; c_st[0] = c0[base0];
        h_st[1] = h0[base1]; c_st[1] = c0[base1];
    }

    // ---- publish h0 into buf[0] (ALL slots: zeros for k>=HD; 8B atomic stores) ----
    {
        int i0 = (int)(unsigned short)f2bf(kok ? h_st[0] : 0.f);
        int i1 = (int)(unsigned short)f2bf(kok ? h_st[1] : 0.f);
        int a0 = __shfl_down(i0, 1), c0s = __shfl_down(i0, 2), d0 = __shfl_down(i0, 3);
        int a1 = __shfl_down(i1, 1), c1s = __shfl_down(i1, 2), d1 = __shfl_down(i1, 3);
        if ((lk & 3) == 0) {
            unsigned long long p0 = (unsigned long long)(unsigned)(i0 | (a0 << 16))
                                  | ((unsigned long long)(unsigned)(c0s | (d0 << 16)) << 32);
            unsigned long long p1 = (unsigned long long)(unsigned)(i1 | (a1 << 16))
                                  | ((unsigned long long)(unsigned)(c1s | (d1 << 16)) << 32);
            int idx0 = bsl * 512 + (b0v + 16 * (lk >> 3)) * 8 + (lk & 7);
            int idx1 = bsl * 512 + (b1v + 16 * (lk >> 3)) * 8 + (lk & 7);
            __hip_atomic_store((unsigned long long*)(hdir + idx0), p0,
                               __ATOMIC_RELAXED, __HIP_MEMORY_SCOPE_AGENT);
            __hip_atomic_store((unsigned long long*)(hdir + idx1), p1,
                               __ATOMIC_RELAXED, __HIP_MEMORY_SCOPE_AGENT);
        }
    }

    // ---- G prefetch state: gate-packed dwordx2 per (b,k) + masks ----
    u32x2 ga = {0, 0}, gb = {0, 0};
    int m[2]; m[0] = m[1] = 0;
    int lastTile = -1;

    // ---- step-0 gate + prefetch (loads left in flight; poll's vmcnt(0) covers) ----
    {
        int t = dir ? (L - 1) : 0;
        if (gcnt) {
            int tile = dir * 64 + (t >> 3);
            while (__hip_atomic_load(&gcnt[tile], __ATOMIC_RELAXED,
                                     __HIP_MEMORY_SCOPE_AGENT) < 32) {}
            lastTile = tile;
        }
        if (kok) {
            const unsigned short* gr0 = Gd + ((size_t)t * BB + b0v) * 2000 + (size_t)k * 4;
            const unsigned short* gr1 = Gd + ((size_t)t * BB + b1v) * 2000 + (size_t)k * 4;
            asm volatile(
                "global_load_dwordx2 %0, %2, off sc0 sc1\n\t"
                "global_load_dwordx2 %1, %3, off sc0 sc1"
                : "=&v"(ga), "=&v"(gb) : "v"(gr0), "v"(gr1) : "memory");
            m[0] = x[b0v * TT + t] > 0;
            m[1] = x[b1v * TT + t] > 0;
        }
    }

    for (int s = 0; s < L; ++s) {
        const int t = dir ? (L - 1 - s) : s;
        const unsigned short* bufr = hdir + (size_t)s * 8192;
        unsigned short* bufw = hdir + (size_t)(s + 1) * 8192;

        // ---- poll-stage buf[s] into LDS; in-flight G loads ride the vmcnt(0) ----
        {
            const unsigned short* p0 = bufr + (tid +   0) * 8;
            const unsigned short* p1 = bufr + (tid + 256) * 8;
            const unsigned short* p2 = bufr + (tid + 512) * 8;
            const unsigned short* p3 = bufr + (tid + 768) * 8;
            u32x4 c0v, c1v, c2v, c3v;
            for (;;) {
                asm volatile(
                    "global_load_dwordx4 %0, %6, off sc0 sc1\n\t"
                    "global_load_dwordx4 %1, %7, off sc0 sc1\n\t"
                    "global_load_dwordx4 %2, %8, off sc0 sc1\n\t"
                    "global_load_dwordx4 %3, %9, off sc0 sc1\n\t"
                    "s_waitcnt vmcnt(0)"
                    : "=&v"(c0v), "=&v"(c1v), "=&v"(c2v), "=&v"(c3v),
                      "+v"(ga), "+v"(gb)
                    : "v"(p0), "v"(p1), "v"(p2), "v"(p3)
                    : "memory");
                unsigned bad = 0;
#pragma unroll
                for (int q = 0; q < 4; ++q)
                    bad |= (c0v[q] == SENT32) | (c1v[q] == SENT32)
                         | (c2v[q] == SENT32) | (c3v[q] == SENT32);
                if (!bad) break;
            }
            *(u32x4*)&hstage[(tid +   0) * 8] = c0v;
            *(u32x4*)&hstage[(tid + 256) * 8] = c1v;
            *(u32x4*)&hstage[(tid + 512) * 8] = c2v;
            *(u32x4*)&hstage[(tid + 768) * 8] = c3v;
        }
        __syncthreads();

        // ---- recurrent preactivation via MFMA (A fragments from LDS) ----
        f32x4 acc0 = {0.f, 0.f, 0.f, 0.f};
        f32x4 acc1 = {0.f, 0.f, 0.f, 0.f};
#pragma unroll
        for (int ks = 0; ks < 16; ++ks) {
            short8 a = *(const short8*)&hstage[ks * 512 + lane * 8];
            acc0 = __builtin_amdgcn_mfma_f32_16x16x32_bf16(a, bf[0][ks], acc0, 0, 0, 0);
            acc1 = __builtin_amdgcn_mfma_f32_16x16x32_bf16(a, bf[1][ks], acc1, 0, 0, 0);
        }

        // ---- scatter D to LDS: sg[gate][lk][b] ----
        {
            int r0 = (w * 2 + 0) * 16 + nl;
            int r1 = (w * 2 + 1) * 16 + nl;
            int g0r = r0 >> 5, lk0 = r0 & 31;
            int g1r = r1 >> 5, lk1 = r1 & 31;
#pragma unroll
            for (int reg = 0; reg < 4; ++reg) {
                int b = quad * 4 + reg;
                sg[g0r][lk0][b] = acc0[reg];
                sg[g1r][lk1][b] = acc1[reg];
            }
        }
        __syncthreads();

        // ---- epilogue: gates + state update (fast transcendentals), publish ASAP,
        //      then Hout (off the peers' critical path) ----
        int i0 = 0, i1 = 0;
        if (kok) {
            {
                unsigned w0 = ga[0], w1 = ga[1];
                float si  = sg[0][lk][b0v] + h2f((unsigned short)(w0 & 0xffffu));
                float sf  = sg[1][lk][b0v] + h2f((unsigned short)(w0 >> 16));
                float sgg = sg[2][lk][b0v] + h2f((unsigned short)(w1 & 0xffffu));
                float so  = sg[3][lk][b0v] + h2f((unsigned short)(w1 >> 16));
                float c_new = sigm_fast(sf) * c_st[0] + sigm_fast(si) * tanh_fast(sgg);
                float h_new = sigm_fast(so) * tanh_fast(c_new);
                if (m[0]) { h_st[0] = h_new; c_st[0] = c_new; }
            }
            {
                unsigned w0 = gb[0], w1 = gb[1];
                float si  = sg[0][lk][b1v] + h2f((unsigned short)(w0 & 0xffffu));
                float sf  = sg[1][lk][b1v] + h2f((unsigned short)(w0 >> 16));
                float sgg = sg[2][lk][b1v] + h2f((unsigned short)(w1 & 0xffffu));
                float so  = sg[3][lk][b1v] + h2f((unsigned short)(w1 >> 16));
                float c_new = sigm_fast(sf) * c_st[1] + sigm_fast(si) * tanh_fast(sgg);
                float h_new = sigm_fast(so) * tanh_fast(c_new);
                if (m[1]) { h_st[1] = h_new; c_st[1] = c_new; }
            }
            i0 = (int)(unsigned short)f2bf(h_st[0]);
            i1 = (int)(unsigned short)f2bf(h_st[1]);
        }

        // ---- publish h into buf[s+1] (ALL slots; 8B atomic stores; no barrier) ----
        {
            int a0 = __shfl_down(i0, 1), c0s = __shfl_down(i0, 2), d0 = __shfl_down(i0, 3);
            int a1 = __shfl_down(i1, 1), c1s = __shfl_down(i1, 2), d1 = __shfl_down(i1, 3);
            if ((lk & 3) == 0) {
                unsigned long long p0 = (unsigned long long)(unsigned)(i0 | (a0 << 16))
                                      | ((unsigned long long)(unsigned)(c0s | (d0 << 16)) << 32);
                unsigned long long p1 = (unsigned long long)(unsigned)(i1 | (a1 << 16))
                                      | ((unsigned long long)(unsigned)(c1s | (d1 << 16)) << 32);
                int idx0 = bsl * 512 + (b0v + 16 * (lk >> 3)) * 8 + (lk & 7);
                int idx1 = bsl * 512 + (b1v + 16 * (lk >> 3)) * 8 + (lk & 7);
                __hip_atomic_store((unsigned long long*)(bufw + idx0), p0,
                                   __ATOMIC_RELAXED, __HIP_MEMORY_SCOPE_AGENT);
                __hip_atomic_store((unsigned long long*)(bufw + idx1), p1,
                                   __ATOMIC_RELAXED, __HIP_MEMORY_SCOPE_AGENT);
            }
        }

        // ---- Hout (bf16, stride 1024): same bits as published; after publish ----
        if (kok) {
            Hout[((size_t)t * BB + b0v) * 1024 + dir * HD + k] =
                (unsigned short)(m[0] ? i0 : 0);
            Hout[((size_t)t * BB + b1v) * 1024 + dir * HD + k] =
                (unsigned short)(m[1] ? i1 : 0);
        }

        // ---- prefetch next step's G (gated per row-tile) + mask ----
        if (s + 1 < L) {
            int tn = dir ? (L - 2 - s) : (s + 1);
            if (gcnt) {
                int tile = dir * 64 + (tn >> 3);
                if (tile != lastTile) {
                    while (__hip_atomic_load(&gcnt[tile], __ATOMIC_RELAXED,
                                             __HIP_MEMORY_SCOPE_AGENT) < 32) {}
                    lastTile = tile;
                }
            }
            if (kok) {
                const unsigned short* gr0 = Gd + ((size_t)tn * BB + b0v) * 2000 + (size_t)k * 4;
                const unsigned short* gr1 = Gd + ((size_t)tn * BB + b1v) * 2000 + (size_t)k * 4;
                asm volatile(
                    "global_load_dwordx2 %0, %2, off sc0 sc1\n\t"
                    "global_load_dwordx2 %1, %3, off sc0 sc1"
                    : "=&v"(ga), "=&v"(gb) : "v"(gr0), "v"(gr1) : "memory");
                m[0] = x[b0v * TT + tn] > 0;
                m[1] = x[b1v * TT + tn] > 0;
            }
        }
    }
}

// -------- FUSED layer: blocks 0..31 = recurrence (counter-gated G); blocks
// 32..4127 = input-projection GEMM tiles releasing counters. Deadlock-free: gemm
// blocks never wait; rec blocks are first in dispatch order. z=1 tiles processed in
// DESCENDING bx so the backward direction's high-t tiles are produced first. --------
__global__ __launch_bounds__(256, 1) void fused_kernel(
    const unsigned short* __restrict__ A, const unsigned short* __restrict__ Wb,
    const float* __restrict__ b1, const float* __restrict__ b2,
    unsigned short* __restrict__ Gh, int Kpad,
    const float* __restrict__ Whh, const int* __restrict__ x,
    const float* __restrict__ h0, const float* __restrict__ c0, int layerbase,
    unsigned short* __restrict__ Hout, unsigned short* __restrict__ hseq,
    const int* __restrict__ mlen, int* gcnt) {
    int bid = blockIdx.x;
    if (bid < 32) {
        rec_body(Gh, Whh, x, h0, c0, layerbase, Hout, hseq, mlen, gcnt, bid);
    } else {
        int gx = bid - 32;          // 0..4095
        int z = gx & 1;
        int rem = gx >> 1;          // 0..2047
        int bx = rem >> 5;          // 0..63  (by varies fastest)
        int by = rem & 31;          // 0..31
        if (z) bx = 63 - bx;        // backward dir: high-t tiles first
        gemm_body(A, Wb, b1, b2, Gh, Kpad, bx, by, z, gcnt);
    }
}

// -------- output projection: Y (T,B,32) = bf16HS @ Wo^T + bo, masked ----------------
__global__ __launch_bounds__(256) void outproj_kernel(
    const unsigned short* __restrict__ HS, const float* __restrict__ Wo,
    const float* __restrict__ bo, const int* __restrict__ x,
    float* __restrict__ Y) {
    __shared__ float wlds[8 * 1000];
    const int bid = blockIdx.x;          // 1024 blocks
    const int tid = threadIdx.x;         // 256
    const int rblk = bid >> 2;           // 0..255
    const int n0 = (bid & 3) * 8;        // 0,8,16,24
    for (int i = tid; i < 8000; i += 256) {
        int nn = i / 1000;
        int q = i - nn * 1000;
        wlds[i] = Wo[(size_t)(n0 + nn) * 1000 + q];
    }
    __syncthreads();
    const int r = rblk * 32 + (tid >> 3);
    const int n = n0 + (tid & 7);
    const int t = r >> 4;
    const int b = r & 15;
    float out = 0.f;
    if (x[b * TT + t] > 0) {
        const unsigned short* h = HS + (size_t)r * 1024;
        const float* wrow = &wlds[(tid & 7) * 1000];
        float s = 0.f;
#pragma unroll 4
        for (int q = 0; q < 1000; q += 8) {
            short8 hv = *(const short8*)(h + q);
            float4 w0 = *(const float4*)(wrow + q);
            float4 w1 = *(const float4*)(wrow + q + 4);
            s += bf2f((unsigned short)hv[0]) * w0.x + bf2f((unsigned short)hv[1]) * w0.y
               + bf2f((unsigned short)hv[2]) * w0.z + bf2f((unsigned short)hv[3]) * w0.w
               + bf2f((unsigned short)hv[4]) * w1.x + bf2f((unsigned short)hv[5]) * w1.y
               + bf2f((unsigned short)hv[6]) * w1.z + bf2f((unsigned short)hv[7]) * w1.w;
        }
        out = s + bo[n];
    }
    Y[(size_t)r * 32 + n] = out;
}

// ---------------- CRF: gold score + forward scan (single-barrier, prefetched) ------
__global__ __launch_bounds__(1024) void crf_kernel(
    const float* __restrict__ Y, const int* __restrict__ x, const int* __restrict__ y0,
    const float* __restrict__ trans, float* __restrict__ out_pb) {
    int b = blockIdx.x;
    int tid = threadIdx.x;
    int i = tid >> 5;
    int j = tid & 31;
    float tr_ij = trans[i * 32 + j];

    __shared__ float scb[2][32];
    __shared__ float wred[16];
    __shared__ float goldS;

    float gp = 0.f;
    if (tid < TT) {
        int t = tid;
        int xm = x[b * TT + t];
        float mf = (xm > 0) ? 1.f : 0.f;
        int ynext = y0[b * TT + t];
        int yprev = (t == 0) ? 1 : y0[b * TT + t - 1];
        gp = Y[((size_t)t * BB + b) * 32 + ynext] + trans[ynext * 32 + yprev] * mf;
    }
#pragma unroll
    for (int d = 32; d >= 1; d >>= 1) gp += __shfl_down(gp, d);
    if ((tid & 63) == 0) wred[tid >> 6] = gp;
    __syncthreads();
    if (tid == 0) {
        float s = 0.f;
        for (int ww = 0; ww < 16; ++ww) s += wred[ww];
        goldS = s;
    }
    if (tid < 32) scb[0][tid] = (tid == 1) ? 0.f : NEG;
    __syncthreads();

    int cur = 0;
    float emit_c = Y[((size_t)0 * BB + b) * 32 + i];
    int mm_c = x[b * TT + 0] > 0;
    for (int t = 0; t < TT; ++t) {
        float emit_n = 0.f;
        int mm_n = 0;
        if (t + 1 < TT) {
            emit_n = Y[((size_t)(t + 1) * BB + b) * 32 + i];
            mm_n = x[b * TT + t + 1] > 0;
        }
        float sj = scb[cur][j];
        float z = sj + tr_ij;
        float mx = z;
#pragma unroll
        for (int d = 16; d >= 1; d >>= 1) mx = fmaxf(mx, __shfl_xor(mx, d));
        float e = __expf(z - mx);
#pragma unroll
        for (int d = 16; d >= 1; d >>= 1) e += __shfl_xor(e, d);
        float cm = sj;
#pragma unroll
        for (int d = 16; d >= 1; d >>= 1) cm = fmaxf(cm, __shfl_xor(cm, d));
        float newv = emit_c + mx + __logf(e);
        if (j == 0) scb[cur ^ 1][i] = mm_c ? newv : cm;
        __syncthreads();
        cur ^= 1;
        emit_c = emit_n;
        mm_c = mm_n;
    }

    if (tid < 32) {
        float v = scb[cur][tid];
        float mx = v;
#pragma unroll
        for (int d = 16; d >= 1; d >>= 1) mx = fmaxf(mx, __shfl_xor(mx, d));
        float e = __expf(v - mx);
#pragma unroll
        for (int d = 16; d >= 1; d >>= 1) e += __shfl_xor(e, d);
        if (tid == 0) out_pb[b] = (mx + __logf(e)) - goldS;
    }
}

__global__ void final_kernel(const float* __restrict__ out_pb, float* __restrict__ out) {
    if (threadIdx.x == 0 && blockIdx.x == 0) {
        float s = 0.f;
        for (int b = 0; b < BB; ++b) s += out_pb[b];
        out[0] = s / (float)BB;
    }
}

extern "C" void kernel_launch(void* const* d_in, const int* in_sizes, int n_in,
                              void* d_out, int out_size, void* d_ws, size_t ws_size,
                              hipStream_t stream) {
    const int*   x     = (const int*)d_in[0];
    const int*   y0    = (const int*)d_in[1];
    const float* EW    = (const float*)d_in[2];
    const float* Wih0  = (const float*)d_in[3];
    const float* Whh0  = (const float*)d_in[4];
    const float* bih0  = (const float*)d_in[5];
    const float* bhh0  = (const float*)d_in[6];
    const float* Wih1  = (const float*)d_in[7];
    const float* Whh1  = (const float*)d_in[8];
    const float* bih1  = (const float*)d_in[9];
    const float* bhh1  = (const float*)d_in[10];
    const float* Wo    = (const float*)d_in[11];
    const float* bo    = (const float*)d_in[12];
    const float* trans = (const float*)d_in[13];
    const float* h0    = (const float*)d_in[14];
    const float* c0    = (const float*)d_in[15];

    float* ws = (float*)d_ws;
    // Layout (float offsets), total 31,803,521 floats = 127.2 MB:
    //   [0, 524288)            XS bf16 (8192x128); Y fp32(262144)+crfbuf alias
    //   [524288, 16908288)     Gh: fp16 (2, 8192, 2000) GATE-PACKED [row][k*4+gate]
    //   [16908288, 21102592)   H0 bf16 (8192 x 1024)
    //   [21102592, 25296896)   HS bf16 (8192 x 1024)
    //   [25296896, 25552896)   Wb0 bf16 (2,2000,128)
    //   [25552896, 27600896)   Wb1 bf16 (2,2000,1024)
    //   [27600896, 31803392)   hseq: 2 dirs x 513 x 8192 bf16 (shared by both layers)
    //   [31803392]             mlen (1 int)
    //   [31803393, 31803521)   gcnt: tile counters (2 dirs x 64 row-tiles)
    unsigned short* XS = (unsigned short*)ws;
    float* Y      = ws;
    float* crfbuf = ws + 262144;
    unsigned short* Gh   = (unsigned short*)(ws + 524288);
    unsigned short* H0b  = (unsigned short*)(ws + 16908288);
    unsigned short* HSb  = (unsigned short*)(ws + 21102592);
    unsigned short* Wb0  = (unsigned short*)(ws + 25296896);
    unsigned short* Wb1  = (unsigned short*)(ws + 25552896);
    unsigned short* hseq = (unsigned short*)(ws + 27600896);
    int* mlen     = (int*)(ws + 31803392);
    int* gcnt     = (int*)(ws + 31803393);
    const int nsent64 = 2 * (TT + 1) * 8192 / 4;   // 2,101,248 u64 words

    // Phase 0: ONE prep dispatch (maxlen + sentfill#1 + gcnt + embed + wconv x2 + padzero)
    const int nprep = 1 + NSENT64B + NEMB + NWC0 + NWC1 + NPAD;
    prep_kernel<<<nprep, 256, 0, stream>>>(x, mlen, (unsigned long long*)hseq, gcnt,
                                           EW, XS, Wih0, Wb0, Wih1, Wb1, (int*)H0b);

    // Phase 1: FUSED layer-0 GEMM (Kpad=128) + recurrence -> bf16 H0
    fused_kernel<<<32 + 4096, 256, 0, stream>>>(XS, Wb0, bih0, bhh0, Gh, 128,
                                                Whh0, x, h0, c0, 0, H0b, hseq, mlen, gcnt);

    // Phase 2: refill hseq sentinels + re-zero tile counters
    sentfill_kernel<<<(nsent64 + 255) / 256, 256, 0, stream>>>((unsigned long long*)hseq, nsent64, gcnt);

    // Phase 3: FUSED layer-1 GEMM (Kpad=1024) + recurrence -> bf16 HS
    fused_kernel<<<32 + 4096, 256, 0, stream>>>(H0b, Wb1, bih1, bhh1, Gh, 1024,
                                                Whh1, x, h0, c0, 2, HSb, hseq, mlen, gcnt);

    // Phase 4: output projection (masked; bf16 HS, stride 1024; Wo staged in LDS)
    outproj_kernel<<<1024, 256, 0, stream>>>(HSb, Wo, bo, x, Y);

    // Phase 5: CRF gold + forward scan
    crf_kernel<<<BB, 1024, 0, stream>>>(Y, x, y0, trans, crfbuf);

    // Phase 6: mean
    final_kernel<<<1, 64, 0, stream>>>(crfbuf, (float*)d_out);
}

// Round 7
// 2614.539 us; speedup vs baseline: 1.0245x; 1.0245x over previous
//
#include <hip/hip_runtime.h>
#include <hip/hip_fp16.h>
#include <math.h>

#define TT 512
#define BB 16
#define EE 100
#define HD 500
#define NEG (-10000.0f)
#define SENT64 0xFFFFFFFFFFFFFFFFull
#define SENT32 0xFFFFFFFFu

typedef __attribute__((ext_vector_type(8))) short short8;
typedef __attribute__((ext_vector_type(4))) float f32x4;
typedef __attribute__((ext_vector_type(4))) unsigned int u32x4;
typedef __attribute__((ext_vector_type(2))) unsigned int u32x2;

__device__ inline short f2bf(float f) {
    unsigned u = __builtin_bit_cast(unsigned, f);
    unsigned r = (u + 0x7fffu + ((u >> 16) & 1u)) >> 16;
    return (short)r;
}
__device__ inline unsigned short f2h(float f) {
    __half h = __float2half(f);
    return __builtin_bit_cast(unsigned short, h);
}
__device__ inline float h2f(unsigned short u) {
    __half h = __builtin_bit_cast(__half, u);
    return __half2float(h);
}
__device__ inline float bf2f(unsigned short u) {
    return __builtin_bit_cast(float, ((unsigned)u) << 16);
}
// fast sigmoid/tanh via v_exp+v_rcp (r2/r5-verified: absmax 0.0). Saturation correct:
// exp overflow -> inf -> rcp -> 0 -> +/-1.
__device__ inline float sigm_fast(float x) {
    return __builtin_amdgcn_rcpf(1.f + __expf(-x));
}
__device__ inline float tanh_fast(float x) {
    return 1.f - 2.f * __builtin_amdgcn_rcpf(__expf(2.f * x) + 1.f);
}
// MALL write-through 2B store (same visibility mechanics as the h-publish stores)
__device__ inline void store_u16_wt(unsigned short* p, unsigned short v) {
    asm volatile("global_store_short %0, %1, off sc0 sc1" :: "v"(p), "v"((unsigned)v) : "memory");
}

// ============ PREP: maxlen + sentfill + gcnt-zero + embed + wconv x2 + padzero =====
// All tasks are mutually independent; one dispatch replaces six. Block-range switch.
// ROUND-7: wconv now PERMUTES weight rows to gate-packed order (packed col = kk*4+g
// holds logical gate row g*500+kk) so the GEMM writes Gh linearly coalesced (fixes
// r6's 3x write amplification: WRITE_SIZE 292MB -> ~100MB) while the rec consumer
// keeps its dwordx2 gate-packed loads.
#define NSENT64B 8208     // ceil(2101248/256)
#define NEMB     4096
#define NWC0     2000
#define NWC1     16000
#define NPAD     384
__global__ __launch_bounds__(256) void prep_kernel(
    const int* __restrict__ x, int* __restrict__ mlen,
    unsigned long long* __restrict__ sentp, int* __restrict__ gcnt,
    const float* __restrict__ EW, unsigned short* __restrict__ XS,
    const float* __restrict__ Wih0, unsigned short* __restrict__ Wb0,
    const float* __restrict__ Wih1, unsigned short* __restrict__ Wb1,
    int* __restrict__ H0pad) {
    int bid = blockIdx.x;
    int tid = threadIdx.x;
    if (bid == 0) {
        // maxlen (t = tid and tid+256) + gcnt zero
        __shared__ int mx;
        if (tid == 0) mx = 1;
        if (tid < 128)
            __hip_atomic_store(gcnt + tid, 0, __ATOMIC_RELAXED, __HIP_MEMORY_SCOPE_AGENT);
        __syncthreads();
        int any0 = 0, any1 = 0;
        for (int b = 0; b < BB; ++b) {
            any0 |= (x[b * TT + tid] > 0);
            any1 |= (x[b * TT + tid + 256] > 0);
        }
        if (any0) atomicMax(&mx, tid + 1);
        if (any1) atomicMax(&mx, tid + 257);
        __syncthreads();
        if (tid == 0) mlen[0] = mx;
        return;
    }
    bid -= 1;
    if (bid < NSENT64B) {
        int i = bid * 256 + tid;
        if (i < 2101248)
            __hip_atomic_store(sentp + i, SENT64, __ATOMIC_RELAXED, __HIP_MEMORY_SCOPE_AGENT);
        return;
    }
    bid -= NSENT64B;
    if (bid < NEMB) {
        int idx = bid * 256 + tid;       // < 8192*128
        int e = idx & 127;
        int r = idx >> 7;
        int t = r >> 4;
        int b = r & 15;
        unsigned short v = 0;
        if (e < EE) {
            int tok = x[b * TT + t];
            v = (unsigned short)f2bf(EW[(size_t)tok * EE + e]);
        }
        XS[idx] = v;
        return;
    }
    bid -= NEMB;
    if (bid < NWC0) {
        int i = bid * 256 + tid;         // < 512000, Ksrc=100 Kpad=128
        int r = i >> 7;                  // packed dest row in [0,4000)
        int k = i & 127;
        int z = r / 2000;
        int rl = r - z * 2000;           // packed col = kk*4+g
        int logical = (rl & 3) * 500 + (rl >> 2);
        Wb0[i] = (k < 100)
            ? (unsigned short)f2bf(Wih0[((size_t)z * 2000 + logical) * 100 + k]) : 0;
        return;
    }
    bid -= NWC0;
    if (bid < NWC1) {
        int i = bid * 256 + tid;         // < 4096000, Ksrc=1000 Kpad=1024
        int r = i >> 10;                 // packed dest row in [0,4000)
        int k = i & 1023;
        int z = r / 2000;
        int rl = r - z * 2000;
        int logical = (rl & 3) * 500 + (rl >> 2);
        Wb1[i] = (k < 1000)
            ? (unsigned short)f2bf(Wih1[((size_t)z * 2000 + logical) * 1000 + k]) : 0;
        return;
    }
    bid -= NWC1;
    {
        int i = bid * 256 + tid;         // < 98304
        if (i < 8192 * 12) {
            int r = i / 12, c = i - r * 12;
            H0pad[r * 512 + 500 + c] = 0;
        }
    }
}

// ------- sentinel refill between layers (also re-zeroes tile counters) -------------
__global__ void sentfill_kernel(unsigned long long* __restrict__ p, int n,
                                int* __restrict__ cnt) {
    int i = blockIdx.x * 256 + threadIdx.x;
    if (i < n)
        __hip_atomic_store(p + i, SENT64, __ATOMIC_RELAXED, __HIP_MEMORY_SCOPE_AGENT);
    if (cnt && blockIdx.x == 0 && threadIdx.x < 128)
        __hip_atomic_store(cnt + threadIdx.x, 0, __ATOMIC_RELAXED, __HIP_MEMORY_SCOPE_AGENT);
}

// ------------- bf16 MFMA GEMM body (fused producer) --------------------------------
// A: (8192, Kpad) bf16. W: (2, 2000, Kpad) bf16, rows PRE-PERMUTED to gate-packed
// order. Output column n IS the packed column (kk*4+gate) -> linear coalesced
// write-through stores (r5-level coalescing). Bias lookup permuted: logical gate row
// = (n&3)*500 + (n>>2). vmcnt drain, then release counter[z*64+bx].
__device__ __forceinline__ void gemm_body(
    const unsigned short* __restrict__ A, const unsigned short* __restrict__ W,
    const float* __restrict__ b1, const float* __restrict__ b2,
    unsigned short* __restrict__ C, int Kpad, int bx, int by, int z,
    int* gcnt) {
    __shared__ __align__(16) unsigned short AsS[128 * 40];
    __shared__ __align__(16) unsigned short WsS[64 * 40];
    const int tid = threadIdx.x;
    const int lane = tid & 63;
    const int w = tid >> 6;
    const int quad = lane >> 4;
    const int nl = lane & 15;
    const int bm0 = bx * 128;
    const int n0 = by * 64;

    const unsigned short* Wz = W + (size_t)z * 2000 * Kpad;
    unsigned short* Cz = C + (size_t)z * 8192 * 2000;
    const float* b1z = b1 + (size_t)z * 2000;
    const float* b2z = b2 + (size_t)z * 2000;

    f32x4 acc[2][4];
#pragma unroll
    for (int mt = 0; mt < 2; ++mt)
#pragma unroll
        for (int nt = 0; nt < 4; ++nt) acc[mt][nt] = (f32x4){0.f, 0.f, 0.f, 0.f};

    const int arow = tid >> 2;
    const int kc = tid & 3;
    const int wn = n0 + arow;
    const bool wok = (wn < 2000);

    const unsigned short* Ap0 = A + (size_t)(bm0 + arow) * Kpad + kc * 8;
    const unsigned short* Ap1 = A + (size_t)(bm0 + 64 + arow) * Kpad + kc * 8;
    const unsigned short* Wp  = Wz + (size_t)(wok ? wn : 0) * Kpad + kc * 8;

    // preload tile 0
    short8 av0 = *(const short8*)(Ap0);
    short8 av1 = *(const short8*)(Ap1);
    short8 wv = {0, 0, 0, 0, 0, 0, 0, 0};
    if (wok) wv = *(const short8*)(Wp);

    for (int k0 = 0; k0 < Kpad; k0 += 32) {
        __syncthreads();           // prior iteration's fragment reads done (WAR)
        *(short8*)&AsS[arow * 40 + kc * 8] = av0;
        *(short8*)&AsS[(64 + arow) * 40 + kc * 8] = av1;
        *(short8*)&WsS[arow * 40 + kc * 8] = wv;
        __syncthreads();

        // issue next tile's loads now; latency hides under LDS reads + MFMA
        if (k0 + 32 < Kpad) {
            av0 = *(const short8*)(Ap0 + k0 + 32);
            av1 = *(const short8*)(Ap1 + k0 + 32);
            if (wok) wv = *(const short8*)(Wp + k0 + 32);
        }

        short8 af[2], bfr[4];
#pragma unroll
        for (int mt = 0; mt < 2; ++mt)
            af[mt] = *(const short8*)&AsS[(w * 32 + mt * 16 + nl) * 40 + quad * 8];
#pragma unroll
        for (int nt = 0; nt < 4; ++nt)
            bfr[nt] = *(const short8*)&WsS[(nt * 16 + nl) * 40 + quad * 8];
#pragma unroll
        for (int mt = 0; mt < 2; ++mt)
#pragma unroll
            for (int nt = 0; nt < 4; ++nt)
                acc[mt][nt] = __builtin_amdgcn_mfma_f32_16x16x32_bf16(
                    af[mt], bfr[nt], acc[mt][nt], 0, 0, 0);
    }

#pragma unroll
    for (int nt = 0; nt < 4; ++nt) {
        int n = n0 + nt * 16 + nl;       // n IS the packed column (kk*4 + gate)
        if (n < 2000) {
            int lg = n & 3, kk = n >> 2;
            float bb = b1z[lg * 500 + kk] + b2z[lg * 500 + kk];
#pragma unroll
            for (int mt = 0; mt < 2; ++mt) {
                int mbase = bm0 + w * 32 + mt * 16 + quad * 4;
#pragma unroll
                for (int reg = 0; reg < 4; ++reg)
                    store_u16_wt(&Cz[(size_t)(mbase + reg) * 2000 + n],
                                 f2h(acc[mt][nt][reg] + bb));
            }
        }
    }
    // drain asm stores, block-wide complete, release tile counter (agent atomic)
    asm volatile("s_waitcnt vmcnt(0)" ::: "memory");
    __syncthreads();
    if (tid == 0)
        __hip_atomic_fetch_add(&gcnt[z * 64 + bx], 1,
                               __ATOMIC_RELAXED, __HIP_MEMORY_SCOPE_AGENT);
}

// ---------------- persistent-weight recurrence, bf16 MFMA, DATA-IS-FLAG sync -------
// Proven protocol (r0/r4/r5). G is gate-packed: one dwordx2 per (b,k) yields all 4
// gates; loads issued sc0sc1, completion folded into the poll's vmcnt(0) via "+v".
// gcnt gating: before prefetching a NEW 8-step row tile, spin until
// counter[dir*64+tile] == 32 (all 32 column tiles written through). ~once per 8 steps.
__device__ __forceinline__ void rec_body(
    const unsigned short* __restrict__ G, const float* __restrict__ Whh,
    const int* __restrict__ x, const float* __restrict__ h0,
    const float* __restrict__ c0, int layerbase,
    unsigned short* __restrict__ Hout, unsigned short* __restrict__ hseq,
    const int* __restrict__ mlen, int* gcnt, int blk)
{
    const int dir = blk >> 4;
    const int bsl = blk & 15;
    const int k0 = bsl * 32;
    const int tid = threadIdx.x;
    const int lane = tid & 63;
    const int w = tid >> 6;          // wave 0..3
    const int quad = lane >> 4;      // 0..3
    const int nl = lane & 15;
    const int L = mlen[0];           // 1..512

    const float* Wd = Whh + (size_t)dir * 2000 * HD;
    const unsigned short* Gd = G + (size_t)dir * TT * BB * 2000;
    unsigned short* hdir = hseq + (size_t)dir * (TT + 1) * 8192;

    __shared__ __align__(16) unsigned short hstage[8192];
    __shared__ float sg[4][32][17];

    // ---- load weights into registers as B fragments (bf16) ----
    short8 bf[2][16];
#pragma unroll
    for (int tl = 0; tl < 2; ++tl) {
        int tt = w * 2 + tl;
        int r = tt * 16 + nl;          // 0..127 local gate row
        int g = r >> 5;                // gate 0..3
        int lkr = r & 31;
        int kk = k0 + lkr;             // output h index
        const float* wrow = (kk < HD) ? (Wd + (size_t)(g * HD + kk) * HD) : (const float*)0;
#pragma unroll
        for (int ks = 0; ks < 16; ++ks) {
            int kg0 = ks * 32 + quad * 8;
            short8 v;
            if (wrow && kg0 + 8 <= HD) {
                float4 f0 = *(const float4*)(wrow + kg0);
                float4 f1 = *(const float4*)(wrow + kg0 + 4);
                v[0] = f2bf(f0.x); v[1] = f2bf(f0.y); v[2] = f2bf(f0.z); v[3] = f2bf(f0.w);
                v[4] = f2bf(f1.x); v[5] = f2bf(f1.y); v[6] = f2bf(f1.z); v[7] = f2bf(f1.w);
            } else {
#pragma unroll
                for (int j = 0; j < 8; ++j) {
                    int kg = kg0 + j;
                    float f = (wrow && kg < HD) ? wrow[kg] : 0.f;
                    v[j] = f2bf(f);
                }
            }
            bf[tl][ks] = v;
        }
    }

    // ---- per-thread persistent state: 2 (b,k) pairs, same k different b ----
    const int lk = tid & 31;
    const int k  = k0 + lk;
    const bool kok = (k < HD);
    const int b0v = tid >> 5;          // 0..7
    const int b1v = 8 + (tid >> 5);    // 8..15
    float h_st[2] = {0.f, 0.f}, c_st[2] = {0.f, 0.f};
    if (kok) {
        size_t base0 = (size_t)(layerbase + dir) * BB * HD + (size_t)b0v * HD + k;
        size_t base1 = (size_t)(layerbase + dir) * BB * HD + (size_t)b1v * HD + k;
        h_st[0] = h0[base0]; c_st[0] = c0[base0];
        h_st[1] = h0[base1]; c_st[1] = c0[base1];
    }

    // ---- publish h0 into buf[0] (ALL slots: zeros for k>=HD; 8B atomic stores) ----
    {
        int i0 = (int)(unsigned short)f2bf(kok ? h_st[0] : 0.f);
        int i1 = (int)(unsigned short)f2bf(kok ? h_st[1] : 0.f);
        int a0 = __shfl_down(i0, 1), c0s = __shfl_down(i0, 2), d0 = __shfl_down(i0, 3);
        int a1 = __shfl_down(i1, 1), c1s = __shfl_down(i1, 2), d1 = __shfl_down(i1, 3);
        if ((lk & 3) == 0) {
            unsigned long long p0 = (unsigned long long)(unsigned)(i0 | (a0 << 16))
                                  | ((unsigned long long)(unsigned)(c0s | (d0 << 16)) << 32);
            unsigned long long p1 = (unsigned long long)(unsigned)(i1 | (a1 << 16))
                                  | ((unsigned long long)(unsigned)(c1s | (d1 << 16)) << 32);
            int idx0 = bsl * 512 + (b0v + 16 * (lk >> 3)) * 8 + (lk & 7);
            int idx1 = bsl * 512 + (b1v + 16 * (lk >> 3)) * 8 + (lk & 7);
            __hip_atomic_store((unsigned long long*)(hdir + idx0), p0,
                               __ATOMIC_RELAXED, __HIP_MEMORY_SCOPE_AGENT);
            __hip_atomic_store((unsigned long long*)(hdir + idx1), p1,
                               __ATOMIC_RELAXED, __HIP_MEMORY_SCOPE_AGENT);
        }
    }

    // ---- G prefetch state: gate-packed dwordx2 per (b,k) + masks ----
    u32x2 ga = {0, 0}, gb = {0, 0};
    int m[2]; m[0] = m[1] = 0;
    int lastTile = -1;

    // ---- step-0 gate + prefetch (loads left in flight; poll's vmcnt(0) covers) ----
    {
        int t = dir ? (L - 1) : 0;
        if (gcnt) {
            int tile = dir * 64 + (t >> 3);
            while (__hip_atomic_load(&gcnt[tile], __ATOMIC_RELAXED,
                                     __HIP_MEMORY_SCOPE_AGENT) < 32) {}
            lastTile = tile;
        }
        if (kok) {
            const unsigned short* gr0 = Gd + ((size_t)t * BB + b0v) * 2000 + (size_t)k * 4;
            const unsigned short* gr1 = Gd + ((size_t)t * BB + b1v) * 2000 + (size_t)k * 4;
            asm volatile(
                "global_load_dwordx2 %0, %2, off sc0 sc1\n\t"
                "global_load_dwordx2 %1, %3, off sc0 sc1"
                : "=&v"(ga), "=&v"(gb) : "v"(gr0), "v"(gr1) : "memory");
            m[0] = x[b0v * TT + t] > 0;
            m[1] = x[b1v * TT + t] > 0;
        }
    }

    for (int s = 0; s < L; ++s) {
        const int t = dir ? (L - 1 - s) : s;
        const unsigned short* bufr = hdir + (size_t)s * 8192;
        unsigned short* bufw = hdir + (size_t)(s + 1) * 8192;

        // ---- poll-stage buf[s] into LDS; in-flight G loads ride the vmcnt(0) ----
        {
            const unsigned short* p0 = bufr + (tid +   0) * 8;
            const unsigned short* p1 = bufr + (tid + 256) * 8;
            const unsigned short* p2 = bufr + (tid + 512) * 8;
            const unsigned short* p3 = bufr + (tid + 768) * 8;
            u32x4 c0v, c1v, c2v, c3v;
            for (;;) {
                asm volatile(
                    "global_load_dwordx4 %0, %6, off sc0 sc1\n\t"
                    "global_load_dwordx4 %1, %7, off sc0 sc1\n\t"
                    "global_load_dwordx4 %2, %8, off sc0 sc1\n\t"
                    "global_load_dwordx4 %3, %9, off sc0 sc1\n\t"
                    "s_waitcnt vmcnt(0)"
                    : "=&v"(c0v), "=&v"(c1v), "=&v"(c2v), "=&v"(c3v),
                      "+v"(ga), "+v"(gb)
                    : "v"(p0), "v"(p1), "v"(p2), "v"(p3)
                    : "memory");
                unsigned bad = 0;
#pragma unroll
                for (int q = 0; q < 4; ++q)
                    bad |= (c0v[q] == SENT32) | (c1v[q] == SENT32)
                         | (c2v[q] == SENT32) | (c3v[q] == SENT32);
                if (!bad) break;
            }
            *(u32x4*)&hstage[(tid +   0) * 8] = c0v;
            *(u32x4*)&hstage[(tid + 256) * 8] = c1v;
            *(u32x4*)&hstage[(tid + 512) * 8] = c2v;
            *(u32x4*)&hstage[(tid + 768) * 8] = c3v;
        }
        __syncthreads();

        // ---- recurrent preactivation via MFMA (A fragments from LDS) ----
        f32x4 acc0 = {0.f, 0.f, 0.f, 0.f};
        f32x4 acc1 = {0.f, 0.f, 0.f, 0.f};
#pragma unroll
        for (int ks = 0; ks < 16; ++ks) {
            short8 a = *(const short8*)&hstage[ks * 512 + lane * 8];
            acc0 = __builtin_amdgcn_mfma_f32_16x16x32_bf16(a, bf[0][ks], acc0, 0, 0, 0);
            acc1 = __builtin_amdgcn_mfma_f32_16x16x32_bf16(a, bf[1][ks], acc1, 0, 0, 0);
        }

        // ---- scatter D to LDS: sg[gate][lk][b] ----
        {
            int r0 = (w * 2 + 0) * 16 + nl;
            int r1 = (w * 2 + 1) * 16 + nl;
            int g0r = r0 >> 5, lk0 = r0 & 31;
            int g1r = r1 >> 5, lk1 = r1 & 31;
#pragma unroll
            for (int reg = 0; reg < 4; ++reg) {
                int b = quad * 4 + reg;
                sg[g0r][lk0][b] = acc0[reg];
                sg[g1r][lk1][b] = acc1[reg];
            }
        }
        __syncthreads();

        // ---- epilogue: gates + state update (fast transcendentals), publish ASAP,
        //      then Hout (off the peers' critical path) ----
        int i0 = 0, i1 = 0;
        if (kok) {
            {
                unsigned w0 = ga[0], w1 = ga[1];
                float si  = sg[0][lk][b0v] + h2f((unsigned short)(w0 & 0xffffu));
                float sf  = sg[1][lk][b0v] + h2f((unsigned short)(w0 >> 16));
                float sgg = sg[2][lk][b0v] + h2f((unsigned short)(w1 & 0xffffu));
                float so  = sg[3][lk][b0v] + h2f((unsigned short)(w1 >> 16));
                float c_new = sigm_fast(sf) * c_st[0] + sigm_fast(si) * tanh_fast(sgg);
                float h_new = sigm_fast(so) * tanh_fast(c_new);
                if (m[0]) { h_st[0] = h_new; c_st[0] = c_new; }
            }
            {
                unsigned w0 = gb[0], w1 = gb[1];
                float si  = sg[0][lk][b1v] + h2f((unsigned short)(w0 & 0xffffu));
                float sf  = sg[1][lk][b1v] + h2f((unsigned short)(w0 >> 16));
                float sgg = sg[2][lk][b1v] + h2f((unsigned short)(w1 & 0xffffu));
                float so  = sg[3][lk][b1v] + h2f((unsigned short)(w1 >> 16));
                float c_new = sigm_fast(sf) * c_st[1] + sigm_fast(si) * tanh_fast(sgg);
                float h_new = sigm_fast(so) * tanh_fast(c_new);
                if (m[1]) { h_st[1] = h_new; c_st[1] = c_new; }
            }
            i0 = (int)(unsigned short)f2bf(h_st[0]);
            i1 = (int)(unsigned short)f2bf(h_st[1]);
        }

        // ---- publish h into buf[s+1] (ALL slots; 8B atomic stores; no barrier) ----
        {
            int a0 = __shfl_down(i0, 1), c0s = __shfl_down(i0, 2), d0 = __shfl_down(i0, 3);
            int a1 = __shfl_down(i1, 1), c1s = __shfl_down(i1, 2), d1 = __shfl_down(i1, 3);
            if ((lk & 3) == 0) {
                unsigned long long p0 = (unsigned long long)(unsigned)(i0 | (a0 << 16))
                                      | ((unsigned long long)(unsigned)(c0s | (d0 << 16)) << 32);
                unsigned long long p1 = (unsigned long long)(unsigned)(i1 | (a1 << 16))
                                      | ((unsigned long long)(unsigned)(c1s | (d1 << 16)) << 32);
                int idx0 = bsl * 512 + (b0v + 16 * (lk >> 3)) * 8 + (lk & 7);
                int idx1 = bsl * 512 + (b1v + 16 * (lk >> 3)) * 8 + (lk & 7);
                __hip_atomic_store((unsigned long long*)(bufw + idx0), p0,
                                   __ATOMIC_RELAXED, __HIP_MEMORY_SCOPE_AGENT);
                __hip_atomic_store((unsigned long long*)(bufw + idx1), p1,
                                   __ATOMIC_RELAXED, __HIP_MEMORY_SCOPE_AGENT);
            }
        }

        // ---- Hout (bf16, stride 1024): same bits as published; after publish ----
        if (kok) {
            Hout[((size_t)t * BB + b0v) * 1024 + dir * HD + k] =
                (unsigned short)(m[0] ? i0 : 0);
            Hout[((size_t)t * BB + b1v) * 1024 + dir * HD + k] =
                (unsigned short)(m[1] ? i1 : 0);
        }

        // ---- prefetch next step's G (gated per row-tile) + mask ----
        if (s + 1 < L) {
            int tn = dir ? (L - 2 - s) : (s + 1);
            if (gcnt) {
                int tile = dir * 64 + (tn >> 3);
                if (tile != lastTile) {
                    while (__hip_atomic_load(&gcnt[tile], __ATOMIC_RELAXED,
                                             __HIP_MEMORY_SCOPE_AGENT) < 32) {}
                    lastTile = tile;
                }
            }
            if (kok) {
                const unsigned short* gr0 = Gd + ((size_t)tn * BB + b0v) * 2000 + (size_t)k * 4;
                const unsigned short* gr1 = Gd + ((size_t)tn * BB + b1v) * 2000 + (size_t)k * 4;
                asm volatile(
                    "global_load_dwordx2 %0, %2, off sc0 sc1\n\t"
                    "global_load_dwordx2 %1, %3, off sc0 sc1"
                    : "=&v"(ga), "=&v"(gb) : "v"(gr0), "v"(gr1) : "memory");
                m[0] = x[b0v * TT + tn] > 0;
                m[1] = x[b1v * TT + tn] > 0;
            }
        }
    }
}

// -------- FUSED layer: blocks 0..31 = recurrence (counter-gated G); blocks
// 32..4127 = input-projection GEMM tiles releasing counters. Deadlock-free: gemm
// blocks never wait; rec blocks are first in dispatch order. z=1 tiles processed in
// DESCENDING bx so the backward direction's high-t tiles are produced first. --------
__global__ __launch_bounds__(256, 1) void fused_kernel(
    const unsigned short* __restrict__ A, const unsigned short* __restrict__ Wb,
    const float* __restrict__ b1, const float* __restrict__ b2,
    unsigned short* __restrict__ Gh, int Kpad,
    const float* __restrict__ Whh, const int* __restrict__ x,
    const float* __restrict__ h0, const float* __restrict__ c0, int layerbase,
    unsigned short* __restrict__ Hout, unsigned short* __restrict__ hseq,
    const int* __restrict__ mlen, int* gcnt) {
    int bid = blockIdx.x;
    if (bid < 32) {
        rec_body(Gh, Whh, x, h0, c0, layerbase, Hout, hseq, mlen, gcnt, bid);
    } else {
        int gx = bid - 32;          // 0..4095
        int z = gx & 1;
        int rem = gx >> 1;          // 0..2047
        int bx = rem >> 5;          // 0..63  (by varies fastest)
        int by = rem & 31;          // 0..31
        if (z) bx = 63 - bx;        // backward dir: high-t tiles first
        gemm_body(A, Wb, b1, b2, Gh, Kpad, bx, by, z, gcnt);
    }
}

// -------- output projection: Y (T,B,32) = bf16HS @ Wo^T + bo, masked ----------------
__global__ __launch_bounds__(256) void outproj_kernel(
    const unsigned short* __restrict__ HS, const float* __restrict__ Wo,
    const float* __restrict__ bo, const int* __restrict__ x,
    float* __restrict__ Y) {
    __shared__ float wlds[8 * 1000];
    const int bid = blockIdx.x;          // 1024 blocks
    const int tid = threadIdx.x;         // 256
    const int rblk = bid >> 2;           // 0..255
    const int n0 = (bid & 3) * 8;        // 0,8,16,24
    for (int i = tid; i < 8000; i += 256) {
        int nn = i / 1000;
        int q = i - nn * 1000;
        wlds[i] = Wo[(size_t)(n0 + nn) * 1000 + q];
    }
    __syncthreads();
    const int r = rblk * 32 + (tid >> 3);
    const int n = n0 + (tid & 7);
    const int t = r >> 4;
    const int b = r & 15;
    float out = 0.f;
    if (x[b * TT + t] > 0) {
        const unsigned short* h = HS + (size_t)r * 1024;
        const float* wrow = &wlds[(tid & 7) * 1000];
        float s = 0.f;
#pragma unroll 4
        for (int q = 0; q < 1000; q += 8) {
            short8 hv = *(const short8*)(h + q);
            float4 w0 = *(const float4*)(wrow + q);
            float4 w1 = *(const float4*)(wrow + q + 4);
            s += bf2f((unsigned short)hv[0]) * w0.x + bf2f((unsigned short)hv[1]) * w0.y
               + bf2f((unsigned short)hv[2]) * w0.z + bf2f((unsigned short)hv[3]) * w0.w
               + bf2f((unsigned short)hv[4]) * w1.x + bf2f((unsigned short)hv[5]) * w1.y
               + bf2f((unsigned short)hv[6]) * w1.z + bf2f((unsigned short)hv[7]) * w1.w;
        }
        out = s + bo[n];
    }
    Y[(size_t)r * 32 + n] = out;
}

// ---------------- CRF: gold score + forward scan (single-barrier, prefetched) ------
__global__ __launch_bounds__(1024) void crf_kernel(
    const float* __restrict__ Y, const int* __restrict__ x, const int* __restrict__ y0,
    const float* __restrict__ trans, float* __restrict__ out_pb) {
    int b = blockIdx.x;
    int tid = threadIdx.x;
    int i = tid >> 5;
    int j = tid & 31;
    float tr_ij = trans[i * 32 + j];

    __shared__ float scb[2][32];
    __shared__ float wred[16];
    __shared__ float goldS;

    float gp = 0.f;
    if (tid < TT) {
        int t = tid;
        int xm = x[b * TT + t];
        float mf = (xm > 0) ? 1.f : 0.f;
        int ynext = y0[b * TT + t];
        int yprev = (t == 0) ? 1 : y0[b * TT + t - 1];
        gp = Y[((size_t)t * BB + b) * 32 + ynext] + trans[ynext * 32 + yprev] * mf;
    }
#pragma unroll
    for (int d = 32; d >= 1; d >>= 1) gp += __shfl_down(gp, d);
    if ((tid & 63) == 0) wred[tid >> 6] = gp;
    __syncthreads();
    if (tid == 0) {
        float s = 0.f;
        for (int ww = 0; ww < 16; ++ww) s += wred[ww];
        goldS = s;
    }
    if (tid < 32) scb[0][tid] = (tid == 1) ? 0.f : NEG;
    __syncthreads();

    int cur = 0;
    float emit_c = Y[((size_t)0 * BB + b) * 32 + i];
    int mm_c = x[b * TT + 0] > 0;
    for (int t = 0; t < TT; ++t) {
        float emit_n = 0.f;
        int mm_n = 0;
        if (t + 1 < TT) {
            emit_n = Y[((size_t)(t + 1) * BB + b) * 32 + i];
            mm_n = x[b * TT + t + 1] > 0;
        }
        float sj = scb[cur][j];
        float z = sj + tr_ij;
        float mx = z;
#pragma unroll
        for (int d = 16; d >= 1; d >>= 1) mx = fmaxf(mx, __shfl_xor(mx, d));
        float e = __expf(z - mx);
#pragma unroll
        for (int d = 16; d >= 1; d >>= 1) e += __shfl_xor(e, d);
        float cm = sj;
#pragma unroll
        for (int d = 16; d >= 1; d >>= 1) cm = fmaxf(cm, __shfl_xor(cm, d));
        float newv = emit_c + mx + __logf(e);
        if (j == 0) scb[cur ^ 1][i] = mm_c ? newv : cm;
        __syncthreads();
        cur ^= 1;
        emit_c = emit_n;
        mm_c = mm_n;
    }

    if (tid < 32) {
        float v = scb[cur][tid];
        float mx = v;
#pragma unroll
        for (int d = 16; d >= 1; d >>= 1) mx = fmaxf(mx, __shfl_xor(mx, d));
        float e = __expf(v - mx);
#pragma unroll
        for (int d = 16; d >= 1; d >>= 1) e += __shfl_xor(e, d);
        if (tid == 0) out_pb[b] = (mx + __logf(e)) - goldS;
    }
}

__global__ void final_kernel(const float* __restrict__ out_pb, float* __restrict__ out) {
    if (threadIdx.x == 0 && blockIdx.x == 0) {
        float s = 0.f;
        for (int b = 0; b < BB; ++b) s += out_pb[b];
        out[0] = s / (float)BB;
    }
}

extern "C" void kernel_launch(void* const* d_in, const int* in_sizes, int n_in,
                              void* d_out, int out_size, void* d_ws, size_t ws_size,
                              hipStream_t stream) {
    const int*   x     = (const int*)d_in[0];
    const int*   y0    = (const int*)d_in[1];
    const float* EW    = (const float*)d_in[2];
    const float* Wih0  = (const float*)d_in[3];
    const float* Whh0  = (const float*)d_in[4];
    const float* bih0  = (const float*)d_in[5];
    const float* bhh0  = (const float*)d_in[6];
    const float* Wih1  = (const float*)d_in[7];
    const float* Whh1  = (const float*)d_in[8];
    const float* bih1  = (const float*)d_in[9];
    const float* bhh1  = (const float*)d_in[10];
    const float* Wo    = (const float*)d_in[11];
    const float* bo    = (const float*)d_in[12];
    const float* trans = (const float*)d_in[13];
    const float* h0    = (const float*)d_in[14];
    const float* c0    = (const float*)d_in[15];

    float* ws = (float*)d_ws;
    // Layout (float offsets), total 31,803,521 floats = 127.2 MB:
    //   [0, 524288)            XS bf16 (8192x128); Y fp32(262144)+crfbuf alias
    //   [524288, 16908288)     Gh: fp16 (2, 8192, 2000) GATE-PACKED [row][k*4+gate]
    //   [16908288, 21102592)   H0 bf16 (8192 x 1024)
    //   [21102592, 25296896)   HS bf16 (8192 x 1024)
    //   [25296896, 25552896)   Wb0 bf16 (2,2000,128) rows gate-pack-permuted
    //   [25552896, 27600896)   Wb1 bf16 (2,2000,1024) rows gate-pack-permuted
    //   [27600896, 31803392)   hseq: 2 dirs x 513 x 8192 bf16 (shared by both layers)
    //   [31803392]             mlen (1 int)
    //   [31803393, 31803521)   gcnt: tile counters (2 dirs x 64 row-tiles)
    unsigned short* XS = (unsigned short*)ws;
    float* Y      = ws;
    float* crfbuf = ws + 262144;
    unsigned short* Gh   = (unsigned short*)(ws + 524288);
    unsigned short* H0b  = (unsigned short*)(ws + 16908288);
    unsigned short* HSb  = (unsigned short*)(ws + 21102592);
    unsigned short* Wb0  = (unsigned short*)(ws + 25296896);
    unsigned short* Wb1  = (unsigned short*)(ws + 25552896);
    unsigned short* hseq = (unsigned short*)(ws + 27600896);
    int* mlen     = (int*)(ws + 31803392);
    int* gcnt     = (int*)(ws + 31803393);
    const int nsent64 = 2 * (TT + 1) * 8192 / 4;   // 2,101,248 u64 words

    // Phase 0: ONE prep dispatch (maxlen + sentfill#1 + gcnt + embed + wconv x2 + padzero)
    const int nprep = 1 + NSENT64B + NEMB + NWC0 + NWC1 + NPAD;
    prep_kernel<<<nprep, 256, 0, stream>>>(x, mlen, (unsigned long long*)hseq, gcnt,
                                           EW, XS, Wih0, Wb0, Wih1, Wb1, (int*)H0b);

    // Phase 1: FUSED layer-0 GEMM (Kpad=128) + recurrence -> bf16 H0
    fused_kernel<<<32 + 4096, 256, 0, stream>>>(XS, Wb0, bih0, bhh0, Gh, 128,
                                                Whh0, x, h0, c0, 0, H0b, hseq, mlen, gcnt);

    // Phase 2: refill hseq sentinels + re-zero tile counters
    sentfill_kernel<<<(nsent64 + 255) / 256, 256, 0, stream>>>((unsigned long long*)hseq, nsent64, gcnt);

    // Phase 3: FUSED layer-1 GEMM (Kpad=1024) + recurrence -> bf16 HS
    fused_kernel<<<32 + 4096, 256, 0, stream>>>(H0b, Wb1, bih1, bhh1, Gh, 1024,
                                                Whh1, x, h0, c0, 2, HSb, hseq, mlen, gcnt);

    // Phase 4: output projection (masked; bf16 HS, stride 1024; Wo staged in LDS)
    outproj_kernel<<<1024, 256, 0, stream>>>(HSb, Wo, bo, x, Y);

    // Phase 5: CRF gold + forward scan
    crf_kernel<<<BB, 1024, 0, stream>>>(Y, x, y0, trans, crfbuf);

    // Phase 6: mean
    final_kernel<<<1, 64, 0, stream>>>(crfbuf, (float*)d_out);
}

// Round 8
// 2392.565 us; speedup vs baseline: 1.1195x; 1.0928x over previous
//
#include <hip/hip_runtime.h>
#include <hip/hip_fp16.h>
#include <math.h>

#define TT 512
#define BB 16
#define EE 100
#define HD 500
#define NEG (-10000.0f)
#define SENT64 0xFFFFFFFFFFFFFFFFull
#define SENT32 0xFFFFFFFFu

typedef __attribute__((ext_vector_type(8))) short short8;
typedef __attribute__((ext_vector_type(4))) float f32x4;
typedef __attribute__((ext_vector_type(4))) unsigned int u32x4;
typedef __attribute__((ext_vector_type(2))) unsigned int u32x2;

__device__ inline short f2bf(float f) {
    unsigned u = __builtin_bit_cast(unsigned, f);
    unsigned r = (u + 0x7fffu + ((u >> 16) & 1u)) >> 16;
    return (short)r;
}
__device__ inline unsigned short f2h(float f) {
    __half h = __float2half(f);
    return __builtin_bit_cast(unsigned short, h);
}
__device__ inline float h2f(unsigned short u) {
    __half h = __builtin_bit_cast(__half, u);
    return __half2float(h);
}
__device__ inline float bf2f(unsigned short u) {
    return __builtin_bit_cast(float, ((unsigned)u) << 16);
}
// fast sigmoid/tanh via v_exp+v_rcp (r2/r5-verified: absmax 0.0). Saturation correct:
// exp overflow -> inf -> rcp -> 0 -> +/-1.
__device__ inline float sigm_fast(float x) {
    return __builtin_amdgcn_rcpf(1.f + __expf(-x));
}
__device__ inline float tanh_fast(float x) {
    return 1.f - 2.f * __builtin_amdgcn_rcpf(__expf(2.f * x) + 1.f);
}
// MALL write-through stores (visibility mechanics proven by Gh pipeline r5-r7)
__device__ inline void store_u16_wt(unsigned short* p, unsigned short v) {
    asm volatile("global_store_short %0, %1, off sc0 sc1" :: "v"(p), "v"((unsigned)v) : "memory");
}
__device__ inline void store_sent16(void* p) {
    u32x4 s = {SENT32, SENT32, SENT32, SENT32};
    asm volatile("global_store_dwordx4 %0, %1, off sc0 sc1" :: "v"(p), "v"(s) : "memory");
}

// ============ PREP: maxlen + sentfill + cnt-zero + embed + wconv0 + padzero ========
// Block-range switch; wconv1 moved into fused0 (round-8). Sentinel fill now uses 16B
// write-through stores (4x fewer ops than the old 8B atomics, same MALL visibility).
#define NSENTB   4104     // 1,050,624 x 16B stores / 256
#define NEMB     4096
#define NWC0     2000
#define NPAD     384
__global__ __launch_bounds__(256) void prep_kernel(
    const int* __restrict__ x, int* __restrict__ mlen,
    unsigned long long* __restrict__ sentp, int* __restrict__ gcnt,
    const float* __restrict__ EW, unsigned short* __restrict__ XS,
    const float* __restrict__ Wih0, unsigned short* __restrict__ Wb0,
    int* __restrict__ H0pad) {
    int bid = blockIdx.x;
    int tid = threadIdx.x;
    if (bid == 0) {
        // maxlen (t = tid and tid+256) + counter zero (gcnt 128 + fcnt)
        __shared__ int mx;
        if (tid == 0) mx = 1;
        if (tid < 132)
            __hip_atomic_store(gcnt + tid, 0, __ATOMIC_RELAXED, __HIP_MEMORY_SCOPE_AGENT);
        __syncthreads();
        int any0 = 0, any1 = 0;
        for (int b = 0; b < BB; ++b) {
            any0 |= (x[b * TT + tid] > 0);
            any1 |= (x[b * TT + tid + 256] > 0);
        }
        if (any0) atomicMax(&mx, tid + 1);
        if (any1) atomicMax(&mx, tid + 257);
        __syncthreads();
        if (tid == 0) mlen[0] = mx;
        return;
    }
    bid -= 1;
    if (bid < NSENTB) {
        int i = bid * 256 + tid;         // < 1,050,624 16B units
        store_sent16((char*)sentp + (size_t)i * 16);
        return;
    }
    bid -= NSENTB;
    if (bid < NEMB) {
        int idx = bid * 256 + tid;       // < 8192*128
        int e = idx & 127;
        int r = idx >> 7;
        int t = r >> 4;
        int b = r & 15;
        unsigned short v = 0;
        if (e < EE) {
            int tok = x[b * TT + t];
            v = (unsigned short)f2bf(EW[(size_t)tok * EE + e]);
        }
        XS[idx] = v;
        return;
    }
    bid -= NEMB;
    if (bid < NWC0) {
        int i = bid * 256 + tid;         // < 512000, Ksrc=100 Kpad=128
        int r = i >> 7;                  // packed dest row in [0,4000)
        int k = i & 127;
        int z = r / 2000;
        int rl = r - z * 2000;           // packed col = kk*4+g
        int logical = (rl & 3) * 500 + (rl >> 2);
        Wb0[i] = (k < 100)
            ? (unsigned short)f2bf(Wih0[((size_t)z * 2000 + logical) * 100 + k]) : 0;
        return;
    }
    bid -= NWC0;
    {
        int i = bid * 256 + tid;         // < 98304
        if (i < 8192 * 12) {
            int r = i / 12, c = i - r * 12;
            H0pad[r * 512 + 500 + c] = 0;
        }
    }
}

// ------- sentinel refill between layers (16B wt stores; re-zeroes counters) --------
__global__ void sentfill_kernel(unsigned long long* __restrict__ p, int n16,
                                int* __restrict__ cnt) {
    int i = blockIdx.x * 256 + threadIdx.x;
    if (i < n16)
        store_sent16((char*)p + (size_t)i * 16);
    if (cnt && blockIdx.x == 0 && threadIdx.x < 132)
        __hip_atomic_store(cnt + threadIdx.x, 0, __ATOMIC_RELAXED, __HIP_MEMORY_SCOPE_AGENT);
}

// ------------- bf16 MFMA GEMM body (fused producer) --------------------------------
// A: (8192, Kpad) bf16. W: (2, 2000, Kpad) bf16, rows PRE-PERMUTED to gate-packed
// order. Output column n IS the packed column (kk*4+gate) -> linear coalesced
// write-through stores. Bias lookup permuted. vmcnt drain, release counter[z*64+bx].
__device__ __forceinline__ void gemm_body(
    const unsigned short* __restrict__ A, const unsigned short* __restrict__ W,
    const float* __restrict__ b1, const float* __restrict__ b2,
    unsigned short* __restrict__ C, int Kpad, int bx, int by, int z,
    int* gcnt) {
    __shared__ __align__(16) unsigned short AsS[128 * 40];
    __shared__ __align__(16) unsigned short WsS[64 * 40];
    const int tid = threadIdx.x;
    const int lane = tid & 63;
    const int w = tid >> 6;
    const int quad = lane >> 4;
    const int nl = lane & 15;
    const int bm0 = bx * 128;
    const int n0 = by * 64;

    const unsigned short* Wz = W + (size_t)z * 2000 * Kpad;
    unsigned short* Cz = C + (size_t)z * 8192 * 2000;
    const float* b1z = b1 + (size_t)z * 2000;
    const float* b2z = b2 + (size_t)z * 2000;

    f32x4 acc[2][4];
#pragma unroll
    for (int mt = 0; mt < 2; ++mt)
#pragma unroll
        for (int nt = 0; nt < 4; ++nt) acc[mt][nt] = (f32x4){0.f, 0.f, 0.f, 0.f};

    const int arow = tid >> 2;
    const int kc = tid & 3;
    const int wn = n0 + arow;
    const bool wok = (wn < 2000);

    const unsigned short* Ap0 = A + (size_t)(bm0 + arow) * Kpad + kc * 8;
    const unsigned short* Ap1 = A + (size_t)(bm0 + 64 + arow) * Kpad + kc * 8;
    const unsigned short* Wp  = Wz + (size_t)(wok ? wn : 0) * Kpad + kc * 8;

    // preload tile 0
    short8 av0 = *(const short8*)(Ap0);
    short8 av1 = *(const short8*)(Ap1);
    short8 wv = {0, 0, 0, 0, 0, 0, 0, 0};
    if (wok) wv = *(const short8*)(Wp);

    for (int k0 = 0; k0 < Kpad; k0 += 32) {
        __syncthreads();           // prior iteration's fragment reads done (WAR)
        *(short8*)&AsS[arow * 40 + kc * 8] = av0;
        *(short8*)&AsS[(64 + arow) * 40 + kc * 8] = av1;
        *(short8*)&WsS[arow * 40 + kc * 8] = wv;
        __syncthreads();

        // issue next tile's loads now; latency hides under LDS reads + MFMA
        if (k0 + 32 < Kpad) {
            av0 = *(const short8*)(Ap0 + k0 + 32);
            av1 = *(const short8*)(Ap1 + k0 + 32);
            if (wok) wv = *(const short8*)(Wp + k0 + 32);
        }

        short8 af[2], bfr[4];
#pragma unroll
        for (int mt = 0; mt < 2; ++mt)
            af[mt] = *(const short8*)&AsS[(w * 32 + mt * 16 + nl) * 40 + quad * 8];
#pragma unroll
        for (int nt = 0; nt < 4; ++nt)
            bfr[nt] = *(const short8*)&WsS[(nt * 16 + nl) * 40 + quad * 8];
#pragma unroll
        for (int mt = 0; mt < 2; ++mt)
#pragma unroll
            for (int nt = 0; nt < 4; ++nt)
                acc[mt][nt] = __builtin_amdgcn_mfma_f32_16x16x32_bf16(
                    af[mt], bfr[nt], acc[mt][nt], 0, 0, 0);
    }

#pragma unroll
    for (int nt = 0; nt < 4; ++nt) {
        int n = n0 + nt * 16 + nl;       // n IS the packed column (kk*4 + gate)
        if (n < 2000) {
            int lg = n & 3, kk = n >> 2;
            float bb = b1z[lg * 500 + kk] + b2z[lg * 500 + kk];
#pragma unroll
            for (int mt = 0; mt < 2; ++mt) {
                int mbase = bm0 + w * 32 + mt * 16 + quad * 4;
#pragma unroll
                for (int reg = 0; reg < 4; ++reg)
                    store_u16_wt(&Cz[(size_t)(mbase + reg) * 2000 + n],
                                 f2h(acc[mt][nt][reg] + bb));
            }
        }
    }
    // drain asm stores, block-wide complete, release tile counter (agent atomic)
    asm volatile("s_waitcnt vmcnt(0)" ::: "memory");
    __syncthreads();
    if (tid == 0)
        __hip_atomic_fetch_add(&gcnt[z * 64 + bx], 1,
                               __ATOMIC_RELAXED, __HIP_MEMORY_SCOPE_AGENT);
}

// ---------------- persistent-weight recurrence, bf16 MFMA, DATA-IS-FLAG sync -------
// Proven protocol (r0/r4/r5/r7). G gate-packed: one dwordx2 per (b,k); loads sc0sc1,
// completion folded into the poll's vmcnt(0) via "+v". gcnt gating once per 8 steps.
__device__ __forceinline__ void rec_body(
    const unsigned short* __restrict__ G, const float* __restrict__ Whh,
    const int* __restrict__ x, const float* __restrict__ h0,
    const float* __restrict__ c0, int layerbase,
    unsigned short* __restrict__ Hout, unsigned short* __restrict__ hseq,
    const int* __restrict__ mlen, int* gcnt, int blk)
{
    const int dir = blk >> 4;
    const int bsl = blk & 15;
    const int k0 = bsl * 32;
    const int tid = threadIdx.x;
    const int lane = tid & 63;
    const int w = tid >> 6;          // wave 0..3
    const int quad = lane >> 4;      // 0..3
    const int nl = lane & 15;
    const int L = mlen[0];           // 1..512

    const float* Wd = Whh + (size_t)dir * 2000 * HD;
    const unsigned short* Gd = G + (size_t)dir * TT * BB * 2000;
    unsigned short* hdir = hseq + (size_t)dir * (TT + 1) * 8192;

    __shared__ __align__(16) unsigned short hstage[8192];
    __shared__ float sg[4][32][17];

    // ---- load weights into registers as B fragments (bf16) ----
    short8 bf[2][16];
#pragma unroll
    for (int tl = 0; tl < 2; ++tl) {
        int tt = w * 2 + tl;
        int r = tt * 16 + nl;          // 0..127 local gate row
        int g = r >> 5;                // gate 0..3
        int lkr = r & 31;
        int kk = k0 + lkr;             // output h index
        const float* wrow = (kk < HD) ? (Wd + (size_t)(g * HD + kk) * HD) : (const float*)0;
#pragma unroll
        for (int ks = 0; ks < 16; ++ks) {
            int kg0 = ks * 32 + quad * 8;
            short8 v;
            if (wrow && kg0 + 8 <= HD) {
                float4 f0 = *(const float4*)(wrow + kg0);
                float4 f1 = *(const float4*)(wrow + kg0 + 4);
                v[0] = f2bf(f0.x); v[1] = f2bf(f0.y); v[2] = f2bf(f0.z); v[3] = f2bf(f0.w);
                v[4] = f2bf(f1.x); v[5] = f2bf(f1.y); v[6] = f2bf(f1.z); v[7] = f2bf(f1.w);
            } else {
#pragma unroll
                for (int j = 0; j < 8; ++j) {
                    int kg = kg0 + j;
                    float f = (wrow && kg < HD) ? wrow[kg] : 0.f;
                    v[j] = f2bf(f);
                }
            }
            bf[tl][ks] = v;
        }
    }

    // ---- per-thread persistent state: 2 (b,k) pairs, same k different b ----
    const int lk = tid & 31;
    const int k  = k0 + lk;
    const bool kok = (k < HD);
    const int b0v = tid >> 5;          // 0..7
    const int b1v = 8 + (tid >> 5);    // 8..15
    float h_st[2] = {0.f, 0.f}, c_st[2] = {0.f, 0.f};
    if (kok) {
        size_t base0 = (size_t)(layerbase + dir) * BB * HD + (size_t)b0v * HD + k;
        size_t base1 = (size_t)(layerbase + dir) * BB * HD + (size_t)b1v * HD + k;
        h_st[0] = h0[base0]; c_st[0] = c0[base0];
        h_st[1] = h0[base1]; c_st[1] = c0[base1];
    }

    // ---- publish h0 into buf[0] (ALL slots: zeros for k>=HD; 8B atomic stores) ----
    {
        int i0 = (int)(unsigned short)f2bf(kok ? h_st[0] : 0.f);
        int i1 = (int)(unsigned short)f2bf(kok ? h_st[1] : 0.f);
        int a0 = __shfl_down(i0, 1), c0s = __shfl_down(i0, 2), d0 = __shfl_down(i0, 3);
        int a1 = __shfl_down(i1, 1), c1s = __shfl_down(i1, 2), d1 = __shfl_down(i1, 3);
        if ((lk & 3) == 0) {
            unsigned long long p0 = (unsigned long long)(unsigned)(i0 | (a0 << 16))
                                  | ((unsigned long long)(unsigned)(c0s | (d0 << 16)) << 32);
            unsigned long long p1 = (unsigned long long)(unsigned)(i1 | (a1 << 16))
                                  | ((unsigned long long)(unsigned)(c1s | (d1 << 16)) << 32);
            int idx0 = bsl * 512 + (b0v + 16 * (lk >> 3)) * 8 + (lk & 7);
            int idx1 = bsl * 512 + (b1v + 16 * (lk >> 3)) * 8 + (lk & 7);
            __hip_atomic_store((unsigned long long*)(hdir + idx0), p0,
                               __ATOMIC_RELAXED, __HIP_MEMORY_SCOPE_AGENT);
            __hip_atomic_store((unsigned long long*)(hdir + idx1), p1,
                               __ATOMIC_RELAXED, __HIP_MEMORY_SCOPE_AGENT);
        }
    }

    // ---- G prefetch state: gate-packed dwordx2 per (b,k) + masks ----
    u32x2 ga = {0, 0}, gb = {0, 0};
    int m[2]; m[0] = m[1] = 0;
    int lastTile = -1;

    // ---- step-0 gate + prefetch (loads left in flight; poll's vmcnt(0) covers) ----
    {
        int t = dir ? (L - 1) : 0;
        if (gcnt) {
            int tile = dir * 64 + (t >> 3);
            while (__hip_atomic_load(&gcnt[tile], __ATOMIC_RELAXED,
                                     __HIP_MEMORY_SCOPE_AGENT) < 32) {}
            lastTile = tile;
        }
        if (kok) {
            const unsigned short* gr0 = Gd + ((size_t)t * BB + b0v) * 2000 + (size_t)k * 4;
            const unsigned short* gr1 = Gd + ((size_t)t * BB + b1v) * 2000 + (size_t)k * 4;
            asm volatile(
                "global_load_dwordx2 %0, %2, off sc0 sc1\n\t"
                "global_load_dwordx2 %1, %3, off sc0 sc1"
                : "=&v"(ga), "=&v"(gb) : "v"(gr0), "v"(gr1) : "memory");
            m[0] = x[b0v * TT + t] > 0;
            m[1] = x[b1v * TT + t] > 0;
        }
    }

    for (int s = 0; s < L; ++s) {
        const int t = dir ? (L - 1 - s) : s;
        const unsigned short* bufr = hdir + (size_t)s * 8192;
        unsigned short* bufw = hdir + (size_t)(s + 1) * 8192;

        // ---- poll-stage buf[s] into LDS; in-flight G loads ride the vmcnt(0) ----
        {
            const unsigned short* p0 = bufr + (tid +   0) * 8;
            const unsigned short* p1 = bufr + (tid + 256) * 8;
            const unsigned short* p2 = bufr + (tid + 512) * 8;
            const unsigned short* p3 = bufr + (tid + 768) * 8;
            u32x4 c0v, c1v, c2v, c3v;
            for (;;) {
                asm volatile(
                    "global_load_dwordx4 %0, %6, off sc0 sc1\n\t"
                    "global_load_dwordx4 %1, %7, off sc0 sc1\n\t"
                    "global_load_dwordx4 %2, %8, off sc0 sc1\n\t"
                    "global_load_dwordx4 %3, %9, off sc0 sc1\n\t"
                    "s_waitcnt vmcnt(0)"
                    : "=&v"(c0v), "=&v"(c1v), "=&v"(c2v), "=&v"(c3v),
                      "+v"(ga), "+v"(gb)
                    : "v"(p0), "v"(p1), "v"(p2), "v"(p3)
                    : "memory");
                unsigned bad = 0;
#pragma unroll
                for (int q = 0; q < 4; ++q)
                    bad |= (c0v[q] == SENT32) | (c1v[q] == SENT32)
                         | (c2v[q] == SENT32) | (c3v[q] == SENT32);
                if (!bad) break;
            }
            *(u32x4*)&hstage[(tid +   0) * 8] = c0v;
            *(u32x4*)&hstage[(tid + 256) * 8] = c1v;
            *(u32x4*)&hstage[(tid + 512) * 8] = c2v;
            *(u32x4*)&hstage[(tid + 768) * 8] = c3v;
        }
        __syncthreads();

        // ---- recurrent preactivation via MFMA (A fragments from LDS) ----
        f32x4 acc0 = {0.f, 0.f, 0.f, 0.f};
        f32x4 acc1 = {0.f, 0.f, 0.f, 0.f};
#pragma unroll
        for (int ks = 0; ks < 16; ++ks) {
            short8 a = *(const short8*)&hstage[ks * 512 + lane * 8];
            acc0 = __builtin_amdgcn_mfma_f32_16x16x32_bf16(a, bf[0][ks], acc0, 0, 0, 0);
            acc1 = __builtin_amdgcn_mfma_f32_16x16x32_bf16(a, bf[1][ks], acc1, 0, 0, 0);
        }

        // ---- scatter D to LDS: sg[gate][lk][b] ----
        {
            int r0 = (w * 2 + 0) * 16 + nl;
            int r1 = (w * 2 + 1) * 16 + nl;
            int g0r = r0 >> 5, lk0 = r0 & 31;
            int g1r = r1 >> 5, lk1 = r1 & 31;
#pragma unroll
            for (int reg = 0; reg < 4; ++reg) {
                int b = quad * 4 + reg;
                sg[g0r][lk0][b] = acc0[reg];
                sg[g1r][lk1][b] = acc1[reg];
            }
        }
        __syncthreads();

        // ---- epilogue: gates + state update (fast transcendentals), publish ASAP,
        //      then Hout (off the peers' critical path) ----
        int i0 = 0, i1 = 0;
        if (kok) {
            {
                unsigned w0 = ga[0], w1 = ga[1];
                float si  = sg[0][lk][b0v] + h2f((unsigned short)(w0 & 0xffffu));
                float sf  = sg[1][lk][b0v] + h2f((unsigned short)(w0 >> 16));
                float sgg = sg[2][lk][b0v] + h2f((unsigned short)(w1 & 0xffffu));
                float so  = sg[3][lk][b0v] + h2f((unsigned short)(w1 >> 16));
                float c_new = sigm_fast(sf) * c_st[0] + sigm_fast(si) * tanh_fast(sgg);
                float h_new = sigm_fast(so) * tanh_fast(c_new);
                if (m[0]) { h_st[0] = h_new; c_st[0] = c_new; }
            }
            {
                unsigned w0 = gb[0], w1 = gb[1];
                float si  = sg[0][lk][b1v] + h2f((unsigned short)(w0 & 0xffffu));
                float sf  = sg[1][lk][b1v] + h2f((unsigned short)(w0 >> 16));
                float sgg = sg[2][lk][b1v] + h2f((unsigned short)(w1 & 0xffffu));
                float so  = sg[3][lk][b1v] + h2f((unsigned short)(w1 >> 16));
                float c_new = sigm_fast(sf) * c_st[1] + sigm_fast(si) * tanh_fast(sgg);
                float h_new = sigm_fast(so) * tanh_fast(c_new);
                if (m[1]) { h_st[1] = h_new; c_st[1] = c_new; }
            }
            i0 = (int)(unsigned short)f2bf(h_st[0]);
            i1 = (int)(unsigned short)f2bf(h_st[1]);
        }

        // ---- publish h into buf[s+1] (ALL slots; 8B atomic stores; no barrier) ----
        {
            int a0 = __shfl_down(i0, 1), c0s = __shfl_down(i0, 2), d0 = __shfl_down(i0, 3);
            int a1 = __shfl_down(i1, 1), c1s = __shfl_down(i1, 2), d1 = __shfl_down(i1, 3);
            if ((lk & 3) == 0) {
                unsigned long long p0 = (unsigned long long)(unsigned)(i0 | (a0 << 16))
                                      | ((unsigned long long)(unsigned)(c0s | (d0 << 16)) << 32);
                unsigned long long p1 = (unsigned long long)(unsigned)(i1 | (a1 << 16))
                                      | ((unsigned long long)(unsigned)(c1s | (d1 << 16)) << 32);
                int idx0 = bsl * 512 + (b0v + 16 * (lk >> 3)) * 8 + (lk & 7);
                int idx1 = bsl * 512 + (b1v + 16 * (lk >> 3)) * 8 + (lk & 7);
                __hip_atomic_store((unsigned long long*)(bufw + idx0), p0,
                                   __ATOMIC_RELAXED, __HIP_MEMORY_SCOPE_AGENT);
                __hip_atomic_store((unsigned long long*)(bufw + idx1), p1,
                                   __ATOMIC_RELAXED, __HIP_MEMORY_SCOPE_AGENT);
            }
        }

        // ---- Hout (bf16, stride 1024): same bits as published; after publish ----
        if (kok) {
            Hout[((size_t)t * BB + b0v) * 1024 + dir * HD + k] =
                (unsigned short)(m[0] ? i0 : 0);
            Hout[((size_t)t * BB + b1v) * 1024 + dir * HD + k] =
                (unsigned short)(m[1] ? i1 : 0);
        }

        // ---- prefetch next step's G (gated per row-tile) + mask ----
        if (s + 1 < L) {
            int tn = dir ? (L - 2 - s) : (s + 1);
            if (gcnt) {
                int tile = dir * 64 + (tn >> 3);
                if (tile != lastTile) {
                    while (__hip_atomic_load(&gcnt[tile], __ATOMIC_RELAXED,
                                             __HIP_MEMORY_SCOPE_AGENT) < 32) {}
                    lastTile = tile;
                }
            }
            if (kok) {
                const unsigned short* gr0 = Gd + ((size_t)tn * BB + b0v) * 2000 + (size_t)k * 4;
                const unsigned short* gr1 = Gd + ((size_t)tn * BB + b1v) * 2000 + (size_t)k * 4;
                asm volatile(
                    "global_load_dwordx2 %0, %2, off sc0 sc1\n\t"
                    "global_load_dwordx2 %1, %3, off sc0 sc1"
                    : "=&v"(ga), "=&v"(gb) : "v"(gr0), "v"(gr1) : "memory");
                m[0] = x[b0v * TT + tn] > 0;
                m[1] = x[b1v * TT + tn] > 0;
            }
        }
    }
}

// -------- FUSED layer: blocks 0..31 = recurrence (counter-gated G); blocks
// 32..4127 = input-projection GEMM tiles releasing counters; blocks 4128+
// (layer 0 only) = wconv1 (Wih1 -> gate-pack-permuted Wb1, consumed by fused1;
// no sync needed). Deadlock-free: only rec blocks wait; they're first. --------
__global__ __launch_bounds__(256, 1) void fused_kernel(
    const unsigned short* __restrict__ A, const unsigned short* __restrict__ Wb,
    const float* __restrict__ b1, const float* __restrict__ b2,
    unsigned short* __restrict__ Gh, int Kpad,
    const float* __restrict__ Whh, const int* __restrict__ x,
    const float* __restrict__ h0, const float* __restrict__ c0, int layerbase,
    unsigned short* __restrict__ Hout, unsigned short* __restrict__ hseq,
    const int* __restrict__ mlen, int* gcnt,
    const float* __restrict__ Wc_src, unsigned short* __restrict__ Wc_dst) {
    int bid = blockIdx.x;
    if (bid < 32) {
        rec_body(Gh, Whh, x, h0, c0, layerbase, Hout, hseq, mlen, gcnt, bid);
    } else if (bid < 32 + 4096) {
        int gx = bid - 32;          // 0..4095
        int z = gx & 1;
        int rem = gx >> 1;          // 0..2047
        int bx = rem >> 5;          // 0..63  (by varies fastest)
        int by = rem & 31;          // 0..31
        if (z) bx = 63 - bx;        // backward dir: high-t tiles first
        gemm_body(A, Wb, b1, b2, Gh, Kpad, bx, by, z, gcnt);
    } else {
        // wconv1: < 4,096,000 elems, Ksrc=1000 Kpad=1024, gate-pack row permute
        int i = (bid - 4128) * 256 + threadIdx.x;
        int r = i >> 10;
        int k = i & 1023;
        int z = r / 2000;
        int rl = r - z * 2000;
        int logical = (rl & 3) * 500 + (rl >> 2);
        Wc_dst[i] = (k < 1000)
            ? (unsigned short)f2bf(Wc_src[((size_t)z * 2000 + logical) * 1000 + k]) : 0;
    }
}

// -------- output projection: Y (T,B,32) = bf16HS @ Wo^T + bo, masked ----------------
__global__ __launch_bounds__(256) void outproj_kernel(
    const unsigned short* __restrict__ HS, const float* __restrict__ Wo,
    const float* __restrict__ bo, const int* __restrict__ x,
    float* __restrict__ Y) {
    __shared__ float wlds[8 * 1000];
    const int bid = blockIdx.x;          // 1024 blocks
    const int tid = threadIdx.x;         // 256
    const int rblk = bid >> 2;           // 0..255
    const int n0 = (bid & 3) * 8;        // 0,8,16,24
    for (int i = tid; i < 8000; i += 256) {
        int nn = i / 1000;
        int q = i - nn * 1000;
        wlds[i] = Wo[(size_t)(n0 + nn) * 1000 + q];
    }
    __syncthreads();
    const int r = rblk * 32 + (tid >> 3);
    const int n = n0 + (tid & 7);
    const int t = r >> 4;
    const int b = r & 15;
    float out = 0.f;
    if (x[b * TT + t] > 0) {
        const unsigned short* h = HS + (size_t)r * 1024;
        const float* wrow = &wlds[(tid & 7) * 1000];
        float s = 0.f;
#pragma unroll 4
        for (int q = 0; q < 1000; q += 8) {
            short8 hv = *(const short8*)(h + q);
            float4 w0 = *(const float4*)(wrow + q);
            float4 w1 = *(const float4*)(wrow + q + 4);
            s += bf2f((unsigned short)hv[0]) * w0.x + bf2f((unsigned short)hv[1]) * w0.y
               + bf2f((unsigned short)hv[2]) * w0.z + bf2f((unsigned short)hv[3]) * w0.w
               + bf2f((unsigned short)hv[4]) * w1.x + bf2f((unsigned short)hv[5]) * w1.y
               + bf2f((unsigned short)hv[6]) * w1.z + bf2f((unsigned short)hv[7]) * w1.w;
        }
        out = s + bo[n];
    }
    Y[(size_t)r * 32 + n] = out;
}

// ---------------- CRF: single-wave-per-batch scan, zero barriers -------------------
// One 64-lane wave per batch: lane l -> (i = l&31, j-half = l>>5, 16 j's each).
// sc[32] lives in LDS; wave lockstep means the per-iter read(all)->write(new)
// sequence needs NO barrier (single PC; ds ordering via compiler waitcnt).
// Masked steps (mask is a prefix by construction) are a fixed point
// (sc <- broadcast-max): apply once, break -- bitwise-identical final state.
// final_kernel folded in: agent-atomic store + vmcnt drain + fetch_add; the
// LAST block sums all 16 in fixed order (deterministic) and writes the mean.
__global__ __launch_bounds__(64) void crf_kernel(
    const float* __restrict__ Y, const int* __restrict__ x, const int* __restrict__ y0,
    const float* __restrict__ trans, float* __restrict__ out_pb,
    float* __restrict__ out, int* __restrict__ fcnt) {
    const int b = blockIdx.x;
    const int lane = threadIdx.x;    // 0..63
    const int i = lane & 31;
    const int half = lane >> 5;
    __shared__ float sc[32];

    // per-lane slice of trans: row i, j in [half*16, half*16+16)
    float tr[16];
#pragma unroll
    for (int jj = 0; jj < 16; ++jj) tr[jj] = trans[i * 32 + half * 16 + jj];

    // gold score: each lane handles t = lane, lane+64, ... (8 t's), wave-reduce
    float gp = 0.f;
    for (int t = lane; t < TT; t += 64) {
        int xm = x[b * TT + t];
        float mf = (xm > 0) ? 1.f : 0.f;
        int ynext = y0[b * TT + t];
        int yprev = (t == 0) ? 1 : y0[b * TT + t - 1];
        gp += Y[((size_t)t * BB + b) * 32 + ynext] + trans[ynext * 32 + yprev] * mf;
    }
#pragma unroll
    for (int d = 32; d >= 1; d >>= 1) gp += __shfl_down(gp, d);
    float goldS = __shfl(gp, 0);

    if (half == 0) sc[i] = (i == 1) ? 0.f : NEG;

    float emit_c = Y[(size_t)b * 32 + i];
    int mm_c = x[b * TT + 0] > 0;
    for (int t = 0; t < TT; ++t) {
        float emit_n = 0.f;
        int mm_n = 0;
        if (t + 1 < TT) {
            emit_n = Y[((size_t)(t + 1) * BB + b) * 32 + i];
            mm_n = x[b * TT + t + 1] > 0;
        }
        const float* sch = &sc[half * 16];
        float4 s0 = *(const float4*)(sch + 0);
        float4 s1 = *(const float4*)(sch + 4);
        float4 s2 = *(const float4*)(sch + 8);
        float4 s3 = *(const float4*)(sch + 12);
        float sj[16] = {s0.x, s0.y, s0.z, s0.w, s1.x, s1.y, s1.z, s1.w,
                        s2.x, s2.y, s2.z, s2.w, s3.x, s3.y, s3.z, s3.w};
        if (mm_c) {        // wave-uniform branch (mask depends on (b,t) only)
            float z[16];
#pragma unroll
            for (int jj = 0; jj < 16; ++jj) z[jj] = sj[jj] + tr[jj];
            float m1 = z[0];
#pragma unroll
            for (int jj = 1; jj < 16; ++jj) m1 = fmaxf(m1, z[jj]);
            float mx = fmaxf(m1, __shfl_xor(m1, 32));
            float e1 = 0.f;
#pragma unroll
            for (int jj = 0; jj < 16; ++jj) e1 += __expf(z[jj] - mx);
            float et = e1 + __shfl_xor(e1, 32);
            float newv = emit_c + mx + __logf(et);
            if (half == 0) sc[i] = newv;
        } else {
            float c1 = sj[0];
#pragma unroll
            for (int jj = 1; jj < 16; ++jj) c1 = fmaxf(c1, sj[jj]);
            float cm = fmaxf(c1, __shfl_xor(c1, 32));
            if (half == 0) sc[i] = cm;
            break;         // fixed point: all later steps are masked no-ops
        }
        emit_c = emit_n;
        mm_c = mm_n;
    }

    // final logsumexp over sc[0..31] (reduce within each 32-lane group)
    float v = sc[i];
    float mx = v;
#pragma unroll
    for (int d = 16; d >= 1; d >>= 1) mx = fmaxf(mx, __shfl_xor(mx, d));
    float e = __expf(v - mx);
#pragma unroll
    for (int d = 16; d >= 1; d >>= 1) e += __shfl_xor(e, d);

    if (lane == 0) {
        float zb = (mx + __logf(e)) - goldS;
        __hip_atomic_store(&out_pb[b], zb, __ATOMIC_RELAXED, __HIP_MEMORY_SCOPE_AGENT);
        asm volatile("s_waitcnt vmcnt(0)" ::: "memory");
        int old = __hip_atomic_fetch_add(fcnt, 1, __ATOMIC_RELAXED,
                                         __HIP_MEMORY_SCOPE_AGENT);
        if (old == BB - 1) {       // last block: deterministic fixed-order mean
            float s = 0.f;
            for (int bb = 0; bb < BB; ++bb)
                s += __hip_atomic_load(&out_pb[bb], __ATOMIC_RELAXED,
                                       __HIP_MEMORY_SCOPE_AGENT);
            out[0] = s / (float)BB;
        }
    }
}

extern "C" void kernel_launch(void* const* d_in, const int* in_sizes, int n_in,
                              void* d_out, int out_size, void* d_ws, size_t ws_size,
                              hipStream_t stream) {
    const int*   x     = (const int*)d_in[0];
    const int*   y0    = (const int*)d_in[1];
    const float* EW    = (const float*)d_in[2];
    const float* Wih0  = (const float*)d_in[3];
    const float* Whh0  = (const float*)d_in[4];
    const float* bih0  = (const float*)d_in[5];
    const float* bhh0  = (const float*)d_in[6];
    const float* Wih1  = (const float*)d_in[7];
    const float* Whh1  = (const float*)d_in[8];
    const float* bih1  = (const float*)d_in[9];
    const float* bhh1  = (const float*)d_in[10];
    const float* Wo    = (const float*)d_in[11];
    const float* bo    = (const float*)d_in[12];
    const float* trans = (const float*)d_in[13];
    const float* h0    = (const float*)d_in[14];
    const float* c0    = (const float*)d_in[15];

    float* ws = (float*)d_ws;
    // Layout (float offsets), total 31,803,525 floats = 127.2 MB:
    //   [0, 524288)            XS bf16 (8192x128); Y fp32(262144)+crfbuf alias
    //   [524288, 16908288)     Gh: fp16 (2, 8192, 2000) GATE-PACKED [row][k*4+gate]
    //   [16908288, 21102592)   H0 bf16 (8192 x 1024)
    //   [21102592, 25296896)   HS bf16 (8192 x 1024)
    //   [25296896, 25552896)   Wb0 bf16 (2,2000,128) rows gate-pack-permuted
    //   [25552896, 27600896)   Wb1 bf16 (2,2000,1024) rows gate-pack-permuted
    //   [27600896, 31803392)   hseq: 2 dirs x 513 x 8192 bf16 (shared by both layers)
    //   [31803392]             mlen (1 int)
    //   [31803393, 31803525)   gcnt: 128 tile counters + fcnt at [128] + slack
    unsigned short* XS = (unsigned short*)ws;
    float* Y      = ws;
    float* crfbuf = ws + 262144;
    unsigned short* Gh   = (unsigned short*)(ws + 524288);
    unsigned short* H0b  = (unsigned short*)(ws + 16908288);
    unsigned short* HSb  = (unsigned short*)(ws + 21102592);
    unsigned short* Wb0  = (unsigned short*)(ws + 25296896);
    unsigned short* Wb1  = (unsigned short*)(ws + 25552896);
    unsigned short* hseq = (unsigned short*)(ws + 27600896);
    int* mlen     = (int*)(ws + 31803392);
    int* gcnt     = (int*)(ws + 31803393);
    int* fcnt     = gcnt + 128;
    const int nsent16 = 2 * (TT + 1) * 8192 / 8;   // 1,050,624 16B units

    // Phase 0: ONE prep dispatch (maxlen + sentfill#1 + counters + embed + wconv0 + padzero)
    const int nprep = 1 + NSENTB + NEMB + NWC0 + NPAD;
    prep_kernel<<<nprep, 256, 0, stream>>>(x, mlen, (unsigned long long*)hseq, gcnt,
                                           EW, XS, Wih0, Wb0, (int*)H0b);

    // Phase 1: FUSED layer-0 GEMM (Kpad=128) + recurrence -> bf16 H0; wconv1 rides
    //          along on idle CUs (blocks 4128..20127)
    fused_kernel<<<32 + 4096 + 16000, 256, 0, stream>>>(
        XS, Wb0, bih0, bhh0, Gh, 128, Whh0, x, h0, c0, 0, H0b, hseq, mlen, gcnt,
        Wih1, Wb1);

    // Phase 2: refill hseq sentinels (16B wt stores) + re-zero counters
    sentfill_kernel<<<NSENTB, 256, 0, stream>>>((unsigned long long*)hseq, nsent16, gcnt);

    // Phase 3: FUSED layer-1 GEMM (Kpad=1024) + recurrence -> bf16 HS
    fused_kernel<<<32 + 4096, 256, 0, stream>>>(
        H0b, Wb1, bih1, bhh1, Gh, 1024, Whh1, x, h0, c0, 2, HSb, hseq, mlen, gcnt,
        nullptr, nullptr);

    // Phase 4: output projection (masked; bf16 HS, stride 1024; Wo staged in LDS)
    outproj_kernel<<<1024, 256, 0, stream>>>(HSb, Wo, bo, x, Y);

    // Phase 5: CRF gold + forward scan (single-wave blocks; mean folded in)
    crf_kernel<<<BB, 64, 0, stream>>>(Y, x, y0, trans, crfbuf, (float*)d_out, fcnt);
}